// Round 15
// baseline (278.427 us; speedup 1.0000x reference)
//
#include <hip/hip_runtime.h>

constexpr int NN = 100000;
constexpr int NE = 3200000;
constexpr int DD = 128;
constexpr int NB = 782;          // ceil(NN/128) buckets of 128 nodes
constexpr int RND = 8192;        // edges binned per block (391 blocks)
#define BN_EPS 1e-5f

typedef __attribute__((ext_vector_type(8))) short bf16x8;
typedef __attribute__((ext_vector_type(4))) float f32x4;
typedef __attribute__((ext_vector_type(2))) float f32x2;

// ---- workspace layout (bytes) ----
constexpr size_t WS_CNT   = 0;            // int[NB]
constexpr size_t WS_COFF  = 4096;         // int[NB+1]
constexpr size_t WS_CUR   = 8192;         // int[NB]
constexpr size_t WS_FLAG  = 12288;        // int[1]
constexpr size_t WS_BNSUM = 12800;        // float[128]
constexpr size_t WS_BNSQ  = 13312;        // float[128]
constexpr size_t WS_ZERO  = 16384;        // memset range
constexpr size_t WS_DEG   = 16384;        // int[NN]
constexpr size_t WS_OFF   = 416384;       // int[NN]
constexpr size_t WS_CSR   = 816384;       // int[NE]
constexpr size_t WS_WT    = 13616384;     // ushort[128*256] transposed bf16 W (64KB)
// d_out first half (out_raw): xq (fp8[NN*128], 12.8MB) at offset 0, dead after
//   k_agg; k_gemm overwrites with x_raw.
// d_out second half (out_bn): bin (uint[NE]) at [0,12.8M) until k_csr;
//   aggb (bf16[NN*128]) at [0,25.6M) from k_agg; xb (bf16[NN*128]) at [25.6M,51.2M).
//   All dead before k_norm writes x_deskewed.

__device__ inline unsigned bf16rne(float f) {
    unsigned u = __float_as_uint(f);
    return (u + 0x7fffu + ((u >> 16) & 1u)) >> 16;
}

#if __has_builtin(__builtin_amdgcn_cvt_pk_f32_fp8)
__device__ inline f32x2 fp8pk_lo(unsigned u) {
    return __builtin_amdgcn_cvt_pk_f32_fp8((int)u, false);
}
__device__ inline f32x2 fp8pk_hi(unsigned u) {
    return __builtin_amdgcn_cvt_pk_f32_fp8((int)u, true);
}
__device__ inline unsigned f32x4_to_fp8(float4 v) {
    int w = __builtin_amdgcn_cvt_pk_fp8_f32(v.x, v.y, 0, false);
    w = __builtin_amdgcn_cvt_pk_fp8_f32(v.z, v.w, w, true);
    return (unsigned)w;
}
#else
__device__ inline float fp8_to_f32_1(unsigned b) {
    unsigned s = (b & 0x80u) << 24;
    unsigned em = b & 0x7fu;
    float f;
    if (em >= 8) f = __uint_as_float((em << 20) + (120u << 23));
    else f = (float)em * 0.001953125f;
    return __uint_as_float(__float_as_uint(f) | s);
}
__device__ inline f32x2 fp8pk_lo(unsigned u) {
    f32x2 r;
    r[0] = fp8_to_f32_1(u & 0xffu);
    r[1] = fp8_to_f32_1((u >> 8) & 0xffu);
    return r;
}
__device__ inline f32x2 fp8pk_hi(unsigned u) {
    f32x2 r;
    r[0] = fp8_to_f32_1((u >> 16) & 0xffu);
    r[1] = fp8_to_f32_1((u >> 24) & 0xffu);
    return r;
}
__device__ inline unsigned f32_to_fp8_1(float f) {
    unsigned s = (__float_as_uint(f) >> 24) & 0x80u;
    float a = fabsf(f);
    if (!(a > 0.f)) return s;
    if (a >= 448.f) return s | 0x7Eu;
    int e = (int)(__float_as_uint(a) >> 23) - 127;
    if (e < -6) e = -6;
    float step = __uint_as_float((unsigned)(e - 3 + 127) << 23);
    int m = (int)rintf(a / step);
    if (m >= 16) { e += 1; m = 8; }
    if (m >= 8) return s | (unsigned)((e + 7) << 3) | (unsigned)(m - 8);
    return s | (unsigned)m;
}
__device__ inline unsigned f32x4_to_fp8(float4 v) {
    return f32_to_fp8_1(v.x) | (f32_to_fp8_1(v.y) << 8) |
           (f32_to_fp8_1(v.z) << 16) | (f32_to_fp8_1(v.w) << 24);
}
#endif

// accumulate 8 fp8 features from a uint2 into 4 packed f32x2 accumulators
// (f32x2 += f32x2 lowers to v_pk_add_f32: 8 VALU instead of 12)
#define ACC8(u)                                                              \
    {                                                                        \
        aa0 += fp8pk_lo((u).x);                                              \
        aa1 += fp8pk_hi((u).x);                                              \
        aa2 += fp8pk_lo((u).y);                                              \
        aa3 += fp8pk_hi((u).y);                                              \
    }

// Detect whether edge_index arrived as int64 (odd int32 words all zero).
__global__ void k_detect(const int* __restrict__ ei, int* __restrict__ flag) {
    int lane = threadIdx.x;
    int v = ei[2 * lane + 1];
    unsigned long long b = __ballot(v == 0);
    if (lane == 0) *flag = (b == ~0ull) ? 1 : 0;
}

// Build bf16 copy (GEMM), fp8 copy (gather), and transposed bf16 W, one kernel.
__global__ __launch_bounds__(256) void k_prep(const float* __restrict__ x,
                                              unsigned* __restrict__ xb,
                                              unsigned* __restrict__ xq,
                                              const float* __restrict__ Wl,
                                              const float* __restrict__ Wr,
                                              unsigned short* __restrict__ Wt) {
    int bid = blockIdx.x;
    if (bid < 2048) {
        int total = NN * DD / 4;
        for (int i = bid * 256 + threadIdx.x; i < total; i += 2048 * 256) {
            float4 v = ((const float4*)x)[i];
            unsigned a = (bf16rne(v.y) << 16) | bf16rne(v.x);
            unsigned b = (bf16rne(v.w) << 16) | bf16rne(v.z);
            ((uint2*)xb)[i] = make_uint2(a, b);
            xq[i] = f32x4_to_fp8(v);
        }
    } else {
        int idx = (bid - 2048) * 256 + threadIdx.x;   // 32768 total
        int n = idx >> 8, k = idx & 255;
        float v = (k < 128) ? Wl[(size_t)k * DD + n] : Wr[(size_t)(k - 128) * DD + n];
        Wt[idx] = (unsigned short)bf16rne(v);
    }
}

// Coarse bucket histogram (782 buckets) via block-LDS hist + one flush.
__global__ __launch_bounds__(256) void k_bcount(const int* __restrict__ ei,
                                                const int* __restrict__ flag,
                                                int* __restrict__ cnt) {
    __shared__ int hist[NB];
    for (int i = threadIdx.x; i < NB; i += 256) hist[i] = 0;
    __syncthreads();
    int i64 = *flag;
    int stride = gridDim.x * 256;
    for (int e = blockIdx.x * 256 + threadIdx.x; e < NE; e += stride) {
        int dst = i64 ? ei[2 * (NE + e)] : ei[NE + e];
        atomicAdd(&hist[dst >> 7], 1);
    }
    __syncthreads();
    for (int i = threadIdx.x; i < NB; i += 256) {
        int c = hist[i];
        if (c) atomicAdd(&cnt[i], c);
    }
}

// Exclusive scan of the 782 bucket counts.
__global__ __launch_bounds__(256) void k_scan(const int* __restrict__ cnt,
                                              int* __restrict__ coff,
                                              int* __restrict__ cur) {
    __shared__ int s[NB];
    for (int i = threadIdx.x; i < NB; i += 256) s[i] = cnt[i];
    __syncthreads();
    if (threadIdx.x == 0) {
        int acc = 0;
        for (int i = 0; i < NB; ++i) { int c = s[i]; s[i] = acc; acc += c; }
    }
    __syncthreads();
    for (int i = threadIdx.x; i < NB; i += 256) { coff[i] = s[i]; cur[i] = s[i]; }
    if (threadIdx.x == 0) coff[NB] = NE;
}

// Bin edges by coarse bucket. In-LDS bucket-sort of edge indices, then a
// COALESCED flush: consecutive threads write consecutive addresses of each
// bucket run.
__global__ __launch_bounds__(256) void k_bin(const int* __restrict__ ei,
                                             const int* __restrict__ flag,
                                             int* __restrict__ cur,
                                             unsigned* __restrict__ bin) {
    __shared__ int hist[NB];
    __shared__ int sbs[NB];
    __shared__ int gbase[NB];
    __shared__ int rk[NB];
    __shared__ int wsum[256];
    __shared__ unsigned short sj[RND];
    int tid = threadIdx.x;
    for (int i = tid; i < NB; i += 256) { hist[i] = 0; rk[i] = 0; }
    __syncthreads();
    int i64 = *flag;
    int e0 = blockIdx.x * RND;
    int cntE = NE - e0; if (cntE > RND) cntE = RND;

    for (int j = tid; j < cntE; j += 256) {
        int e = e0 + j;
        int dst = i64 ? ei[2 * (NE + e)] : ei[NE + e];
        atomicAdd(&hist[dst >> 7], 1);
    }
    __syncthreads();

    int b4 = tid * 4;
    int l0 = (b4 + 0 < NB) ? hist[b4 + 0] : 0;
    int l1 = (b4 + 1 < NB) ? hist[b4 + 1] : 0;
    int l2 = (b4 + 2 < NB) ? hist[b4 + 2] : 0;
    int l3 = (b4 + 3 < NB) ? hist[b4 + 3] : 0;
    int tsum = l0 + l1 + l2 + l3;
    wsum[tid] = tsum;
    __syncthreads();
    for (int d = 1; d < 256; d <<= 1) {
        int v = (tid >= d) ? wsum[tid - d] : 0;
        __syncthreads();
        wsum[tid] += v;
        __syncthreads();
    }
    int p = wsum[tid] - tsum;
    if (b4 + 0 < NB) sbs[b4 + 0] = p;
    if (b4 + 1 < NB) sbs[b4 + 1] = p + l0;
    if (b4 + 2 < NB) sbs[b4 + 2] = p + l0 + l1;
    if (b4 + 3 < NB) sbs[b4 + 3] = p + l0 + l1 + l2;
    __syncthreads();

    for (int j = tid; j < cntE; j += 256) {
        int e = e0 + j;
        int dst = i64 ? ei[2 * (NE + e)] : ei[NE + e];
        int b = dst >> 7;
        int r = atomicAdd(&rk[b], 1);
        sj[sbs[b] + r] = (unsigned short)j;
    }
    for (int b = tid; b < NB; b += 256) {
        int c = hist[b];
        if (c > 0) gbase[b] = atomicAdd(&cur[b], c);
    }
    __syncthreads();

    for (int t = tid; t < cntE; t += 256) {
        int j = sj[t];
        int e = e0 + j;
        int src = i64 ? ei[2 * e] : ei[e];
        int dst = i64 ? ei[2 * (NE + e)] : ei[NE + e];
        int b = dst >> 7;
        bin[gbase[b] + (t - sbs[b])] = ((unsigned)src << 7) | (unsigned)(dst & 127);
    }
}

// Per-bucket counting sort -> node-grouped CSR + deg/off.
__global__ __launch_bounds__(256) void k_csr(const unsigned* __restrict__ bin,
                                             const int* __restrict__ coff,
                                             int* __restrict__ csr,
                                             int* __restrict__ deg,
                                             int* __restrict__ off) {
    __shared__ int hist[128];
    __shared__ int sb[128];
    __shared__ int curs[128];
    int b = blockIdx.x;
    int tid = threadIdx.x;
    if (tid < 128) hist[tid] = 0;
    __syncthreads();
    int e0 = coff[b], e1 = coff[b + 1];
    for (int j = e0 + tid; j < e1; j += 256)
        atomicAdd(&hist[bin[j] & 127], 1);
    __syncthreads();
    if (tid == 0) {
        int acc = 0;
        for (int i = 0; i < 128; ++i) { sb[i] = acc; acc += hist[i]; }
    }
    __syncthreads();
    if (tid < 128) curs[tid] = sb[tid];
    __syncthreads();
    for (int j = e0 + tid; j < e1; j += 256) {
        unsigned p = bin[j];
        int d = p & 127;
        int r = atomicAdd(&curs[d], 1);
        csr[e0 + r] = (int)(p >> 7);
    }
    int n = b * 128 + tid;
    if (tid < 128 && n < NN) {
        deg[n] = hist[tid];
        off[n] = e0 + sb[tid];
    }
}

// Wave-per-node gather-sum from the fp8 copy, 4 rows per wave-load:
// each lane loads a uint2 (8 fp8); 16 lanes cover a 128B row; the 4
// lane-quarters handle 4 edges per instruction; packed f32x2 accumulate.
__global__ __launch_bounds__(256) void k_agg(const uint2* __restrict__ xq2,
                                             const int* __restrict__ csr,
                                             const int* __restrict__ deg,
                                             const int* __restrict__ off,
                                             unsigned* __restrict__ aggb) {
    int w = (blockIdx.x * 256 + threadIdx.x) >> 6;
    int lane = threadIdx.x & 63;
    if (w >= NN) return;
    int dg = deg[w];
    int o = off[w];
    int q = lane >> 4;       // edge sub-slot (0..3)
    int cl = lane & 15;      // uint2 slot within the 128B row
    f32x2 aa0 = {0.f, 0.f}, aa1 = {0.f, 0.f}, aa2 = {0.f, 0.f}, aa3 = {0.f, 0.f};

    int j = 0;
    for (; j + 16 <= dg; j += 16) {
        int s0 = csr[o + j + q];
        int s1 = csr[o + j + 4 + q];
        int s2 = csr[o + j + 8 + q];
        int s3 = csr[o + j + 12 + q];
        uint2 u0 = xq2[(size_t)s0 * 16 + cl];
        uint2 u1 = xq2[(size_t)s1 * 16 + cl];
        uint2 u2 = xq2[(size_t)s2 * 16 + cl];
        uint2 u3 = xq2[(size_t)s3 * 16 + cl];
        ACC8(u0); ACC8(u1); ACC8(u2); ACC8(u3);
    }
    for (; j + 4 <= dg; j += 4) {
        int s = csr[o + j + q];
        uint2 u = xq2[(size_t)s * 16 + cl];
        ACC8(u);
    }
    int rem = dg - j;        // 0..3
    if (q < rem) {
        int s = csr[o + j + q];
        uint2 u = xq2[(size_t)s * 16 + cl];
        ACC8(u);
    }

    float a0 = aa0[0], a1 = aa0[1], a2 = aa1[0], a3 = aa1[1];
    float a4 = aa2[0], a5 = aa2[1], a6 = aa3[0], a7 = aa3[1];
    a0 += __shfl_xor(a0, 16); a0 += __shfl_xor(a0, 32);
    a1 += __shfl_xor(a1, 16); a1 += __shfl_xor(a1, 32);
    a2 += __shfl_xor(a2, 16); a2 += __shfl_xor(a2, 32);
    a3 += __shfl_xor(a3, 16); a3 += __shfl_xor(a3, 32);
    a4 += __shfl_xor(a4, 16); a4 += __shfl_xor(a4, 32);
    a5 += __shfl_xor(a5, 16); a5 += __shfl_xor(a5, 32);
    a6 += __shfl_xor(a6, 16); a6 += __shfl_xor(a6, 32);
    a7 += __shfl_xor(a7, 16); a7 += __shfl_xor(a7, 32);

    if (lane < 16) {
        float inv = 1.0f / fmaxf((float)dg, 1.0f);
        uint4 p;
        p.x = (bf16rne(a1 * inv) << 16) | bf16rne(a0 * inv);  // feats 8cl+0,1
        p.y = (bf16rne(a3 * inv) << 16) | bf16rne(a2 * inv);  // feats 8cl+2,3
        p.z = (bf16rne(a5 * inv) << 16) | bf16rne(a4 * inv);  // feats 8cl+4,5
        p.w = (bf16rne(a7 * inv) << 16) | bf16rne(a6 * inv);  // feats 8cl+6,7
        ((uint4*)aggb)[(size_t)w * 16 + cl] = p;
    }
}

// MFMA GEMM: x_raw = [agg | x]_bf16 @ Wt^T + b, BN stats fused into epilogue.
// Block: 4 waves over 64 rows; wave: 16 rows x 128 cols = 8 tiles of 16x16,
// K=256 in 8 steps (64 MFMAs). 1563 blocks -> ~6 blocks/CU for latency hiding.
__global__ __launch_bounds__(256) void k_gemm(const unsigned short* __restrict__ aggb,
                                              const unsigned short* __restrict__ xb,
                                              const unsigned short* __restrict__ Wt,
                                              const float* __restrict__ bl,
                                              float* __restrict__ out_raw,
                                              float* __restrict__ bn_sum,
                                              float* __restrict__ bn_sq) {
    __shared__ float s_s[4][128];
    __shared__ float s_q[4][128];
    int tid = threadIdx.x;
    int wv = tid >> 6, lane = tid & 63;
    int l15 = lane & 15, lhi = lane >> 4;
    int mr = blockIdx.x * 64 + wv * 16;

    int r0 = mr + l15;       if (r0 > NN - 1) r0 = NN - 1;
    const unsigned short* a0p = aggb + (size_t)r0 * DD;
    const unsigned short* x0p = xb + (size_t)r0 * DD;

    f32x4 acc[8];
    #pragma unroll
    for (int nt = 0; nt < 8; ++nt)
        acc[nt] = (f32x4){0.f, 0.f, 0.f, 0.f};

    #pragma unroll
    for (int ks = 0; ks < 8; ++ks) {
        int kk = (ks & 3) * 32 + lhi * 8;
        bf16x8 a0 = (ks < 4) ? *(const bf16x8*)(a0p + kk)
                             : *(const bf16x8*)(x0p + kk);
        #pragma unroll
        for (int nt = 0; nt < 8; ++nt) {
            bf16x8 b = *(const bf16x8*)(Wt + (size_t)(nt * 16 + l15) * 256 + ks * 32 + lhi * 8);
            acc[nt] = __builtin_amdgcn_mfma_f32_16x16x32_bf16(a0, b, acc[nt], 0, 0, 0);
        }
    }

    // epilogue: bias + store (D layout: row=lhi*4+reg, col=l15) + column stats
    float bias8[8];
    #pragma unroll
    for (int nt = 0; nt < 8; ++nt) bias8[nt] = bl[nt * 16 + l15];

    float s8[8] = {}, q8[8] = {};
    #pragma unroll
    for (int r = 0; r < 4; ++r) {
        int row = mr + lhi * 4 + r;
        if (row < NN) {
            #pragma unroll
            for (int nt = 0; nt < 8; ++nt) {
                float v = acc[nt][r] + bias8[nt];
                out_raw[(size_t)row * DD + nt * 16 + l15] = v;
                s8[nt] += v;
                q8[nt] += v * v;
            }
        }
    }

    // reduce across the 4 lane-groups sharing a column (lane^16, lane^32)
    #pragma unroll
    for (int nt = 0; nt < 8; ++nt) {
        s8[nt] += __shfl_xor(s8[nt], 16);
        s8[nt] += __shfl_xor(s8[nt], 32);
        q8[nt] += __shfl_xor(q8[nt], 16);
        q8[nt] += __shfl_xor(q8[nt], 32);
    }
    if (lhi == 0) {
        #pragma unroll
        for (int nt = 0; nt < 8; ++nt) {
            s_s[wv][nt * 16 + l15] = s8[nt];
            s_q[wv][nt * 16 + l15] = q8[nt];
        }
    }
    __syncthreads();
    if (tid < 128) {
        float ts = s_s[0][tid] + s_s[1][tid] + s_s[2][tid] + s_s[3][tid];
        float tq = s_q[0][tid] + s_q[1][tid] + s_q[2][tid] + s_q[3][tid];
        atomicAdd(&bn_sum[tid], ts);
        atomicAdd(&bn_sq[tid], tq);
    }
}

__global__ __launch_bounds__(256) void k_norm(const float* __restrict__ raw,
                                              const float* __restrict__ bn_sum,
                                              const float* __restrict__ bn_sq,
                                              const float* __restrict__ gamma,
                                              const float* __restrict__ beta,
                                              float* __restrict__ out) {
    const float invN = 1.0f / (float)NN;
    int total = NN * DD / 4;
    for (int idx = blockIdx.x * 256 + threadIdx.x; idx < total; idx += gridDim.x * 256) {
        int cp = idx & 31;
        float4 v = ((const float4*)raw)[idx];
        float4 s = ((const float4*)bn_sum)[cp];
        float4 q = ((const float4*)bn_sq)[cp];
        float4 g = ((const float4*)gamma)[cp];
        float4 b = ((const float4*)beta)[cp];
        float4 o;
        { float mu = s.x * invN; float var = q.x * invN - mu * mu;
          o.x = (v.x - mu) * rsqrtf(var + BN_EPS) * g.x + b.x; }
        { float mu = s.y * invN; float var = q.y * invN - mu * mu;
          o.y = (v.y - mu) * rsqrtf(var + BN_EPS) * g.y + b.y; }
        { float mu = s.z * invN; float var = q.z * invN - mu * mu;
          o.z = (v.z - mu) * rsqrtf(var + BN_EPS) * g.z + b.z; }
        { float mu = s.w * invN; float var = q.w * invN - mu * mu;
          o.w = (v.w - mu) * rsqrtf(var + BN_EPS) * g.w + b.w; }
        ((float4*)out)[idx] = o;
    }
}

extern "C" void kernel_launch(void* const* d_in, const int* in_sizes, int n_in,
                              void* d_out, int out_size, void* d_ws, size_t ws_size,
                              hipStream_t stream) {
    const float* x     = (const float*)d_in[0];
    const int*   ei    = (const int*)d_in[1];
    const float* Wl    = (const float*)d_in[2];
    const float* bl    = (const float*)d_in[3];
    const float* Wr    = (const float*)d_in[4];
    const float* gamma = (const float*)d_in[5];
    const float* beta  = (const float*)d_in[6];

    float* out_raw = (float*)d_out;                       // [NN][DD] x_raw
    float* out_bn  = out_raw + (size_t)NN * DD;           // [NN][DD] x_deskewed
    unsigned* xq   = (unsigned*)d_out;                    // fp8[NN*128] in out_raw half
    unsigned* bin  = (unsigned*)out_bn;                   // uint[NE]
    unsigned* aggb = (unsigned*)out_bn;                   // bf16[NN*128] packed
    unsigned* xb   = (unsigned*)((char*)out_bn + (size_t)NN * DD * 2); // bf16[NN*128]

    char* ws = (char*)d_ws;
    int*   cnt    = (int*)(ws + WS_CNT);
    int*   coff   = (int*)(ws + WS_COFF);
    int*   cur    = (int*)(ws + WS_CUR);
    int*   flag   = (int*)(ws + WS_FLAG);
    float* bn_sum = (float*)(ws + WS_BNSUM);
    float* bn_sq  = (float*)(ws + WS_BNSQ);
    int*   deg    = (int*)(ws + WS_DEG);
    int*   off    = (int*)(ws + WS_OFF);
    int*   csr    = (int*)(ws + WS_CSR);
    unsigned short* Wt = (unsigned short*)(ws + WS_WT);

    hipMemsetAsync(d_ws, 0, WS_ZERO, stream);

    k_detect<<<1, 64, 0, stream>>>(ei, flag);
    k_prep<<<2048 + 128, 256, 0, stream>>>(x, xb, xq, Wl, Wr, Wt);
    k_bcount<<<512, 256, 0, stream>>>(ei, flag, cnt);
    k_scan<<<1, 256, 0, stream>>>(cnt, coff, cur);
    k_bin<<<(NE + RND - 1) / RND, 256, 0, stream>>>(ei, flag, cur, bin);
    k_csr<<<NB, 256, 0, stream>>>(bin, coff, csr, deg, off);
    k_agg<<<(NN * 64 + 255) / 256, 256, 0, stream>>>((const uint2*)xq, csr, deg, off, aggb);
    k_gemm<<<(NN + 63) / 64, 256, 0, stream>>>((const unsigned short*)aggb,
                                               (const unsigned short*)xb,
                                               Wt, bl, out_raw, bn_sum, bn_sq);
    k_norm<<<4096, 256, 0, stream>>>(out_raw, bn_sum, bn_sq, gamma, beta, out_bn);
}

// Round 16
// 262.622 us; speedup vs baseline: 1.0602x; 1.0602x over previous
//
#include <hip/hip_runtime.h>

constexpr int NN = 100000;
constexpr int NE = 3200000;
constexpr int DD = 128;
constexpr int NB = 782;          // ceil(NN/128) buckets of 128 nodes
constexpr int RND = 8192;        // edges binned per block (391 blocks)
#define BN_EPS 1e-5f

typedef __attribute__((ext_vector_type(8))) short bf16x8;
typedef __attribute__((ext_vector_type(4))) float f32x4;
typedef __attribute__((ext_vector_type(2))) float f32x2;

// ---- workspace layout (bytes) ----
constexpr size_t WS_CNT   = 0;            // int[NB]
constexpr size_t WS_COFF  = 4096;         // int[NB+1]
constexpr size_t WS_CUR   = 8192;         // int[NB]
constexpr size_t WS_FLAG  = 12288;        // int[1]
constexpr size_t WS_BNSUM = 12800;        // float[128]
constexpr size_t WS_BNSQ  = 13312;        // float[128]
constexpr size_t WS_ZERO  = 16384;        // memset range
constexpr size_t WS_DEG   = 16384;        // int[NN]
constexpr size_t WS_OFF   = 416384;       // int[NN]
constexpr size_t WS_CSR   = 816384;       // int[NE]
constexpr size_t WS_WT    = 13616384;     // ushort[128*256] transposed bf16 W (64KB)
// d_out first half (out_raw): xq (fp8[NN*128], 12.8MB) at offset 0, dead after
//   k_agg; k_gemm overwrites with x_raw.
// d_out second half (out_bn): bin (uint[NE]) at [0,12.8M) until k_csr;
//   aggb (bf16[NN*128]) at [0,25.6M) from k_agg; xb (bf16[NN*128]) at [25.6M,51.2M).
//   All dead before k_norm writes x_deskewed.

__device__ inline unsigned bf16rne(float f) {
    unsigned u = __float_as_uint(f);
    return (u + 0x7fffu + ((u >> 16) & 1u)) >> 16;
}

#if __has_builtin(__builtin_amdgcn_cvt_pk_f32_fp8)
__device__ inline f32x2 fp8pk_lo(unsigned u) {
    return __builtin_amdgcn_cvt_pk_f32_fp8((int)u, false);
}
__device__ inline f32x2 fp8pk_hi(unsigned u) {
    return __builtin_amdgcn_cvt_pk_f32_fp8((int)u, true);
}
__device__ inline unsigned f32x4_to_fp8(float4 v) {
    int w = __builtin_amdgcn_cvt_pk_fp8_f32(v.x, v.y, 0, false);
    w = __builtin_amdgcn_cvt_pk_fp8_f32(v.z, v.w, w, true);
    return (unsigned)w;
}
#else
__device__ inline float fp8_to_f32_1(unsigned b) {
    unsigned s = (b & 0x80u) << 24;
    unsigned em = b & 0x7fu;
    float f;
    if (em >= 8) f = __uint_as_float((em << 20) + (120u << 23));
    else f = (float)em * 0.001953125f;
    return __uint_as_float(__float_as_uint(f) | s);
}
__device__ inline f32x2 fp8pk_lo(unsigned u) {
    f32x2 r;
    r[0] = fp8_to_f32_1(u & 0xffu);
    r[1] = fp8_to_f32_1((u >> 8) & 0xffu);
    return r;
}
__device__ inline f32x2 fp8pk_hi(unsigned u) {
    f32x2 r;
    r[0] = fp8_to_f32_1((u >> 16) & 0xffu);
    r[1] = fp8_to_f32_1((u >> 24) & 0xffu);
    return r;
}
__device__ inline unsigned f32_to_fp8_1(float f) {
    unsigned s = (__float_as_uint(f) >> 24) & 0x80u;
    float a = fabsf(f);
    if (!(a > 0.f)) return s;
    if (a >= 448.f) return s | 0x7Eu;
    int e = (int)(__float_as_uint(a) >> 23) - 127;
    if (e < -6) e = -6;
    float step = __uint_as_float((unsigned)(e - 3 + 127) << 23);
    int m = (int)rintf(a / step);
    if (m >= 16) { e += 1; m = 8; }
    if (m >= 8) return s | (unsigned)((e + 7) << 3) | (unsigned)(m - 8);
    return s | (unsigned)m;
}
__device__ inline unsigned f32x4_to_fp8(float4 v) {
    return f32_to_fp8_1(v.x) | (f32_to_fp8_1(v.y) << 8) |
           (f32_to_fp8_1(v.z) << 16) | (f32_to_fp8_1(v.w) << 24);
}
#endif

// accumulate 8 fp8 features from a uint2 into 4 packed f32x2 accumulators
#define ACC8(u)                                                              \
    {                                                                        \
        aa0 += fp8pk_lo((u).x);                                              \
        aa1 += fp8pk_hi((u).x);                                              \
        aa2 += fp8pk_lo((u).y);                                              \
        aa3 += fp8pk_hi((u).y);                                              \
    }

// Detect whether edge_index arrived as int64 (odd int32 words all zero).
__global__ void k_detect(const int* __restrict__ ei, int* __restrict__ flag) {
    int lane = threadIdx.x;
    int v = ei[2 * lane + 1];
    unsigned long long b = __ballot(v == 0);
    if (lane == 0) *flag = (b == ~0ull) ? 1 : 0;
}

// Build bf16 copy (GEMM), fp8 copy (gather), and transposed bf16 W, one kernel.
__global__ __launch_bounds__(256) void k_prep(const float* __restrict__ x,
                                              unsigned* __restrict__ xb,
                                              unsigned* __restrict__ xq,
                                              const float* __restrict__ Wl,
                                              const float* __restrict__ Wr,
                                              unsigned short* __restrict__ Wt) {
    int bid = blockIdx.x;
    if (bid < 2048) {
        int total = NN * DD / 4;
        for (int i = bid * 256 + threadIdx.x; i < total; i += 2048 * 256) {
            float4 v = ((const float4*)x)[i];
            unsigned a = (bf16rne(v.y) << 16) | bf16rne(v.x);
            unsigned b = (bf16rne(v.w) << 16) | bf16rne(v.z);
            ((uint2*)xb)[i] = make_uint2(a, b);
            xq[i] = f32x4_to_fp8(v);
        }
    } else {
        int idx = (bid - 2048) * 256 + threadIdx.x;   // 32768 total
        int n = idx >> 8, k = idx & 255;
        float v = (k < 128) ? Wl[(size_t)k * DD + n] : Wr[(size_t)(k - 128) * DD + n];
        Wt[idx] = (unsigned short)bf16rne(v);
    }
}

// Coarse bucket histogram (782 buckets) via block-LDS hist + one flush.
__global__ __launch_bounds__(256) void k_bcount(const int* __restrict__ ei,
                                                const int* __restrict__ flag,
                                                int* __restrict__ cnt) {
    __shared__ int hist[NB];
    for (int i = threadIdx.x; i < NB; i += 256) hist[i] = 0;
    __syncthreads();
    int i64 = *flag;
    int stride = gridDim.x * 256;
    for (int e = blockIdx.x * 256 + threadIdx.x; e < NE; e += stride) {
        int dst = i64 ? ei[2 * (NE + e)] : ei[NE + e];
        atomicAdd(&hist[dst >> 7], 1);
    }
    __syncthreads();
    for (int i = threadIdx.x; i < NB; i += 256) {
        int c = hist[i];
        if (c) atomicAdd(&cnt[i], c);
    }
}

// Exclusive scan of the 782 bucket counts.
__global__ __launch_bounds__(256) void k_scan(const int* __restrict__ cnt,
                                              int* __restrict__ coff,
                                              int* __restrict__ cur) {
    __shared__ int s[NB];
    for (int i = threadIdx.x; i < NB; i += 256) s[i] = cnt[i];
    __syncthreads();
    if (threadIdx.x == 0) {
        int acc = 0;
        for (int i = 0; i < NB; ++i) { int c = s[i]; s[i] = acc; acc += c; }
    }
    __syncthreads();
    for (int i = threadIdx.x; i < NB; i += 256) { coff[i] = s[i]; cur[i] = s[i]; }
    if (threadIdx.x == 0) coff[NB] = NE;
}

// Bin edges by coarse bucket. In-LDS bucket-sort of edge indices, then a
// COALESCED flush.
__global__ __launch_bounds__(256) void k_bin(const int* __restrict__ ei,
                                             const int* __restrict__ flag,
                                             int* __restrict__ cur,
                                             unsigned* __restrict__ bin) {
    __shared__ int hist[NB];
    __shared__ int sbs[NB];
    __shared__ int gbase[NB];
    __shared__ int rk[NB];
    __shared__ int wsum[256];
    __shared__ unsigned short sj[RND];
    int tid = threadIdx.x;
    for (int i = tid; i < NB; i += 256) { hist[i] = 0; rk[i] = 0; }
    __syncthreads();
    int i64 = *flag;
    int e0 = blockIdx.x * RND;
    int cntE = NE - e0; if (cntE > RND) cntE = RND;

    for (int j = tid; j < cntE; j += 256) {
        int e = e0 + j;
        int dst = i64 ? ei[2 * (NE + e)] : ei[NE + e];
        atomicAdd(&hist[dst >> 7], 1);
    }
    __syncthreads();

    int b4 = tid * 4;
    int l0 = (b4 + 0 < NB) ? hist[b4 + 0] : 0;
    int l1 = (b4 + 1 < NB) ? hist[b4 + 1] : 0;
    int l2 = (b4 + 2 < NB) ? hist[b4 + 2] : 0;
    int l3 = (b4 + 3 < NB) ? hist[b4 + 3] : 0;
    int tsum = l0 + l1 + l2 + l3;
    wsum[tid] = tsum;
    __syncthreads();
    for (int d = 1; d < 256; d <<= 1) {
        int v = (tid >= d) ? wsum[tid - d] : 0;
        __syncthreads();
        wsum[tid] += v;
        __syncthreads();
    }
    int p = wsum[tid] - tsum;
    if (b4 + 0 < NB) sbs[b4 + 0] = p;
    if (b4 + 1 < NB) sbs[b4 + 1] = p + l0;
    if (b4 + 2 < NB) sbs[b4 + 2] = p + l0 + l1;
    if (b4 + 3 < NB) sbs[b4 + 3] = p + l0 + l1 + l2;
    __syncthreads();

    for (int j = tid; j < cntE; j += 256) {
        int e = e0 + j;
        int dst = i64 ? ei[2 * (NE + e)] : ei[NE + e];
        int b = dst >> 7;
        int r = atomicAdd(&rk[b], 1);
        sj[sbs[b] + r] = (unsigned short)j;
    }
    for (int b = tid; b < NB; b += 256) {
        int c = hist[b];
        if (c > 0) gbase[b] = atomicAdd(&cur[b], c);
    }
    __syncthreads();

    for (int t = tid; t < cntE; t += 256) {
        int j = sj[t];
        int e = e0 + j;
        int src = i64 ? ei[2 * e] : ei[e];
        int dst = i64 ? ei[2 * (NE + e)] : ei[NE + e];
        int b = dst >> 7;
        bin[gbase[b] + (t - sbs[b])] = ((unsigned)src << 7) | (unsigned)(dst & 127);
    }
}

// Per-bucket counting sort -> node-grouped CSR + deg/off.
__global__ __launch_bounds__(256) void k_csr(const unsigned* __restrict__ bin,
                                             const int* __restrict__ coff,
                                             int* __restrict__ csr,
                                             int* __restrict__ deg,
                                             int* __restrict__ off) {
    __shared__ int hist[128];
    __shared__ int sb[128];
    __shared__ int curs[128];
    int b = blockIdx.x;
    int tid = threadIdx.x;
    if (tid < 128) hist[tid] = 0;
    __syncthreads();
    int e0 = coff[b], e1 = coff[b + 1];
    for (int j = e0 + tid; j < e1; j += 256)
        atomicAdd(&hist[bin[j] & 127], 1);
    __syncthreads();
    if (tid == 0) {
        int acc = 0;
        for (int i = 0; i < 128; ++i) { sb[i] = acc; acc += hist[i]; }
    }
    __syncthreads();
    if (tid < 128) curs[tid] = sb[tid];
    __syncthreads();
    for (int j = e0 + tid; j < e1; j += 256) {
        unsigned p = bin[j];
        int d = p & 127;
        int r = atomicAdd(&curs[d], 1);
        csr[e0 + r] = (int)(p >> 7);
    }
    int n = b * 128 + tid;
    if (tid < 128 && n < NN) {
        deg[n] = hist[tid];
        off[n] = e0 + sb[tid];
    }
}

// Wave-per-node gather-sum from the fp8 copy, 4 rows per wave-load,
// packed f32x2 accumulate.
__global__ __launch_bounds__(256) void k_agg(const uint2* __restrict__ xq2,
                                             const int* __restrict__ csr,
                                             const int* __restrict__ deg,
                                             const int* __restrict__ off,
                                             unsigned* __restrict__ aggb) {
    int w = (blockIdx.x * 256 + threadIdx.x) >> 6;
    int lane = threadIdx.x & 63;
    if (w >= NN) return;
    int dg = deg[w];
    int o = off[w];
    int q = lane >> 4;       // edge sub-slot (0..3)
    int cl = lane & 15;      // uint2 slot within the 128B row
    f32x2 aa0 = {0.f, 0.f}, aa1 = {0.f, 0.f}, aa2 = {0.f, 0.f}, aa3 = {0.f, 0.f};

    int j = 0;
    for (; j + 16 <= dg; j += 16) {
        int s0 = csr[o + j + q];
        int s1 = csr[o + j + 4 + q];
        int s2 = csr[o + j + 8 + q];
        int s3 = csr[o + j + 12 + q];
        uint2 u0 = xq2[(size_t)s0 * 16 + cl];
        uint2 u1 = xq2[(size_t)s1 * 16 + cl];
        uint2 u2 = xq2[(size_t)s2 * 16 + cl];
        uint2 u3 = xq2[(size_t)s3 * 16 + cl];
        ACC8(u0); ACC8(u1); ACC8(u2); ACC8(u3);
    }
    for (; j + 4 <= dg; j += 4) {
        int s = csr[o + j + q];
        uint2 u = xq2[(size_t)s * 16 + cl];
        ACC8(u);
    }
    int rem = dg - j;        // 0..3
    if (q < rem) {
        int s = csr[o + j + q];
        uint2 u = xq2[(size_t)s * 16 + cl];
        ACC8(u);
    }

    float a0 = aa0[0], a1 = aa0[1], a2 = aa1[0], a3 = aa1[1];
    float a4 = aa2[0], a5 = aa2[1], a6 = aa3[0], a7 = aa3[1];
    a0 += __shfl_xor(a0, 16); a0 += __shfl_xor(a0, 32);
    a1 += __shfl_xor(a1, 16); a1 += __shfl_xor(a1, 32);
    a2 += __shfl_xor(a2, 16); a2 += __shfl_xor(a2, 32);
    a3 += __shfl_xor(a3, 16); a3 += __shfl_xor(a3, 32);
    a4 += __shfl_xor(a4, 16); a4 += __shfl_xor(a4, 32);
    a5 += __shfl_xor(a5, 16); a5 += __shfl_xor(a5, 32);
    a6 += __shfl_xor(a6, 16); a6 += __shfl_xor(a6, 32);
    a7 += __shfl_xor(a7, 16); a7 += __shfl_xor(a7, 32);

    if (lane < 16) {
        float inv = 1.0f / fmaxf((float)dg, 1.0f);
        uint4 p;
        p.x = (bf16rne(a1 * inv) << 16) | bf16rne(a0 * inv);
        p.y = (bf16rne(a3 * inv) << 16) | bf16rne(a2 * inv);
        p.z = (bf16rne(a5 * inv) << 16) | bf16rne(a4 * inv);
        p.w = (bf16rne(a7 * inv) << 16) | bf16rne(a6 * inv);
        ((uint4*)aggb)[(size_t)w * 16 + cl] = p;
    }
}

// MFMA GEMM (swapped operands): computes D = Wt_tile x node_tile so each
// thread's 4 acc regs are 4 CONSECUTIVE OUTPUT COLUMNS -> float4 stores.
// Block: 4 waves over 128 rows; wave: 32 nodes (2 streams) x 128 cols,
// K=256 in 8 steps (128 MFMAs). Fragments are the same loads as before.
__global__ __launch_bounds__(256) void k_gemm(const unsigned short* __restrict__ aggb,
                                              const unsigned short* __restrict__ xb,
                                              const unsigned short* __restrict__ Wt,
                                              const float* __restrict__ bl,
                                              float* __restrict__ out_raw,
                                              float* __restrict__ bn_sum,
                                              float* __restrict__ bn_sq) {
    __shared__ float s_s[4][128];
    __shared__ float s_q[4][128];
    int tid = threadIdx.x;
    int wv = tid >> 6, lane = tid & 63;
    int l15 = lane & 15, lhi = lane >> 4;
    int mr = blockIdx.x * 128 + wv * 32;

    int r0 = mr + l15;       if (r0 > NN - 1) r0 = NN - 1;
    int r1 = mr + 16 + l15;  if (r1 > NN - 1) r1 = NN - 1;
    const unsigned short* a0p = aggb + (size_t)r0 * DD;
    const unsigned short* a1p = aggb + (size_t)r1 * DD;
    const unsigned short* x0p = xb + (size_t)r0 * DD;
    const unsigned short* x1p = xb + (size_t)r1 * DD;

    f32x4 acc[2][8];
    #pragma unroll
    for (int m = 0; m < 2; ++m)
        #pragma unroll
        for (int nt = 0; nt < 8; ++nt)
            acc[m][nt] = (f32x4){0.f, 0.f, 0.f, 0.f};

    #pragma unroll
    for (int ks = 0; ks < 8; ++ks) {
        int kk = (ks & 3) * 32 + lhi * 8;
        bf16x8 n0, n1;
        if (ks < 4) {
            n0 = *(const bf16x8*)(a0p + kk);
            n1 = *(const bf16x8*)(a1p + kk);
        } else {
            n0 = *(const bf16x8*)(x0p + kk);
            n1 = *(const bf16x8*)(x1p + kk);
        }
        #pragma unroll
        for (int nt = 0; nt < 8; ++nt) {
            bf16x8 wfrag = *(const bf16x8*)(Wt + (size_t)(nt * 16 + l15) * 256 + ks * 32 + lhi * 8);
            // swapped: A = W rows (l15 = output col base), B = node cols (l15 = node)
            acc[0][nt] = __builtin_amdgcn_mfma_f32_16x16x32_bf16(wfrag, n0, acc[0][nt], 0, 0, 0);
            acc[1][nt] = __builtin_amdgcn_mfma_f32_16x16x32_bf16(wfrag, n1, acc[1][nt], 0, 0, 0);
        }
    }

    // epilogue: D layout (col=l15 -> node, row=lhi*4+r -> output col).
    // Thread owns node (mr + m*16 + l15), cols nt*16 + lhi*4 + [0..4).
    f32x4 sA[8], qA[8];
    #pragma unroll
    for (int nt = 0; nt < 8; ++nt) {
        sA[nt] = (f32x4){0.f, 0.f, 0.f, 0.f};
        qA[nt] = (f32x4){0.f, 0.f, 0.f, 0.f};
    }
    f32x4 b4[8];
    #pragma unroll
    for (int nt = 0; nt < 8; ++nt)
        b4[nt] = *(const f32x4*)&bl[nt * 16 + lhi * 4];

    #pragma unroll
    for (int m = 0; m < 2; ++m) {
        int node = mr + m * 16 + l15;
        if (node < NN) {
            #pragma unroll
            for (int nt = 0; nt < 8; ++nt) {
                f32x4 v = acc[m][nt] + b4[nt];
                *(f32x4*)&out_raw[(size_t)node * DD + nt * 16 + lhi * 4] = v;
                sA[nt] += v;
                qA[nt] += v * v;
            }
        }
    }

    // reduce across the 16 l15 lanes (same column set per lhi group)
    #pragma unroll
    for (int nt = 0; nt < 8; ++nt) {
        #pragma unroll
        for (int r = 0; r < 4; ++r) {
            float s = sA[nt][r], q = qA[nt][r];
            s += __shfl_xor(s, 1); s += __shfl_xor(s, 2);
            s += __shfl_xor(s, 4); s += __shfl_xor(s, 8);
            q += __shfl_xor(q, 1); q += __shfl_xor(q, 2);
            q += __shfl_xor(q, 4); q += __shfl_xor(q, 8);
            if (l15 == 0) {
                s_s[wv][nt * 16 + lhi * 4 + r] = s;
                s_q[wv][nt * 16 + lhi * 4 + r] = q;
            }
        }
    }
    __syncthreads();
    if (tid < 128) {
        float ts = s_s[0][tid] + s_s[1][tid] + s_s[2][tid] + s_s[3][tid];
        float tq = s_q[0][tid] + s_q[1][tid] + s_q[2][tid] + s_q[3][tid];
        atomicAdd(&bn_sum[tid], ts);
        atomicAdd(&bn_sq[tid], tq);
    }
}

__global__ __launch_bounds__(256) void k_norm(const float* __restrict__ raw,
                                              const float* __restrict__ bn_sum,
                                              const float* __restrict__ bn_sq,
                                              const float* __restrict__ gamma,
                                              const float* __restrict__ beta,
                                              float* __restrict__ out) {
    const float invN = 1.0f / (float)NN;
    int total = NN * DD / 4;
    for (int idx = blockIdx.x * 256 + threadIdx.x; idx < total; idx += gridDim.x * 256) {
        int cp = idx & 31;
        float4 v = ((const float4*)raw)[idx];
        float4 s = ((const float4*)bn_sum)[cp];
        float4 q = ((const float4*)bn_sq)[cp];
        float4 g = ((const float4*)gamma)[cp];
        float4 b = ((const float4*)beta)[cp];
        float4 o;
        { float mu = s.x * invN; float var = q.x * invN - mu * mu;
          o.x = (v.x - mu) * rsqrtf(var + BN_EPS) * g.x + b.x; }
        { float mu = s.y * invN; float var = q.y * invN - mu * mu;
          o.y = (v.y - mu) * rsqrtf(var + BN_EPS) * g.y + b.y; }
        { float mu = s.z * invN; float var = q.z * invN - mu * mu;
          o.z = (v.z - mu) * rsqrtf(var + BN_EPS) * g.z + b.z; }
        { float mu = s.w * invN; float var = q.w * invN - mu * mu;
          o.w = (v.w - mu) * rsqrtf(var + BN_EPS) * g.w + b.w; }
        ((float4*)out)[idx] = o;
    }
}

extern "C" void kernel_launch(void* const* d_in, const int* in_sizes, int n_in,
                              void* d_out, int out_size, void* d_ws, size_t ws_size,
                              hipStream_t stream) {
    const float* x     = (const float*)d_in[0];
    const int*   ei    = (const int*)d_in[1];
    const float* Wl    = (const float*)d_in[2];
    const float* bl    = (const float*)d_in[3];
    const float* Wr    = (const float*)d_in[4];
    const float* gamma = (const float*)d_in[5];
    const float* beta  = (const float*)d_in[6];

    float* out_raw = (float*)d_out;                       // [NN][DD] x_raw
    float* out_bn  = out_raw + (size_t)NN * DD;           // [NN][DD] x_deskewed
    unsigned* xq   = (unsigned*)d_out;                    // fp8[NN*128] in out_raw half
    unsigned* bin  = (unsigned*)out_bn;                   // uint[NE]
    unsigned* aggb = (unsigned*)out_bn;                   // bf16[NN*128] packed
    unsigned* xb   = (unsigned*)((char*)out_bn + (size_t)NN * DD * 2); // bf16[NN*128]

    char* ws = (char*)d_ws;
    int*   cnt    = (int*)(ws + WS_CNT);
    int*   coff   = (int*)(ws + WS_COFF);
    int*   cur    = (int*)(ws + WS_CUR);
    int*   flag   = (int*)(ws + WS_FLAG);
    float* bn_sum = (float*)(ws + WS_BNSUM);
    float* bn_sq  = (float*)(ws + WS_BNSQ);
    int*   deg    = (int*)(ws + WS_DEG);
    int*   off    = (int*)(ws + WS_OFF);
    int*   csr    = (int*)(ws + WS_CSR);
    unsigned short* Wt = (unsigned short*)(ws + WS_WT);

    hipMemsetAsync(d_ws, 0, WS_ZERO, stream);

    k_detect<<<1, 64, 0, stream>>>(ei, flag);
    k_prep<<<2048 + 128, 256, 0, stream>>>(x, xb, xq, Wl, Wr, Wt);
    k_bcount<<<512, 256, 0, stream>>>(ei, flag, cnt);
    k_scan<<<1, 256, 0, stream>>>(cnt, coff, cur);
    k_bin<<<(NE + RND - 1) / RND, 256, 0, stream>>>(ei, flag, cur, bin);
    k_csr<<<NB, 256, 0, stream>>>(bin, coff, csr, deg, off);
    k_agg<<<(NN * 64 + 255) / 256, 256, 0, stream>>>((const uint2*)xq, csr, deg, off, aggb);
    k_gemm<<<(NN + 127) / 128, 256, 0, stream>>>((const unsigned short*)aggb,
                                                 (const unsigned short*)xb,
                                                 Wt, bl, out_raw, bn_sum, bn_sq);
    k_norm<<<4096, 256, 0, stream>>>(out_raw, bn_sum, bn_sq, gamma, beta, out_bn);
}

// Round 17
// 227.963 us; speedup vs baseline: 1.2214x; 1.1520x over previous
//
#include <hip/hip_runtime.h>

constexpr int NN = 100000;
constexpr int NE = 3200000;
constexpr int DD = 128;
constexpr int NB = 782;          // ceil(NN/128) buckets of 128 nodes
constexpr int RND = 8192;        // edges binned per block (391 blocks)
#define BN_EPS 1e-5f

typedef __attribute__((ext_vector_type(8))) short bf16x8;
typedef __attribute__((ext_vector_type(4))) float f32x4;
typedef __attribute__((ext_vector_type(2))) float f32x2;

// ---- workspace layout (bytes) ----
constexpr size_t WS_CNT   = 0;            // int[NB]
constexpr size_t WS_COFF  = 4096;         // int[NB+1]
constexpr size_t WS_CUR   = 8192;         // int[NB]
constexpr size_t WS_FLAG  = 12288;        // int[1]
constexpr size_t WS_BNSUM = 12800;        // float[128]
constexpr size_t WS_BNSQ  = 13312;        // float[128]
constexpr size_t WS_ZERO  = 16384;        // memset range
constexpr size_t WS_DEG   = 16384;        // int[NN]
constexpr size_t WS_OFF   = 416384;       // int[NN]
constexpr size_t WS_CSR   = 816384;       // int[NE]
constexpr size_t WS_WT    = 13616384;     // ushort[128*256] transposed bf16 W (64KB)
// d_out first half (out_raw): xq (fp8[NN*128], 12.8MB) at offset 0, dead after
//   k_agg; k_gemm overwrites with x_raw.
// d_out second half (out_bn): bin (uint[NE]) at [0,12.8M) until k_csr;
//   aggb (bf16[NN*128]) at [0,25.6M) from k_agg; xb (bf16[NN*128]) at [25.6M,51.2M).
//   All dead before k_norm writes x_deskewed.

__device__ inline unsigned bf16rne(float f) {
    unsigned u = __float_as_uint(f);
    return (u + 0x7fffu + ((u >> 16) & 1u)) >> 16;
}

#if __has_builtin(__builtin_amdgcn_cvt_pk_f32_fp8)
__device__ inline f32x2 fp8pk_lo(unsigned u) {
    return __builtin_amdgcn_cvt_pk_f32_fp8((int)u, false);
}
__device__ inline f32x2 fp8pk_hi(unsigned u) {
    return __builtin_amdgcn_cvt_pk_f32_fp8((int)u, true);
}
__device__ inline unsigned f32x4_to_fp8(float4 v) {
    int w = __builtin_amdgcn_cvt_pk_fp8_f32(v.x, v.y, 0, false);
    w = __builtin_amdgcn_cvt_pk_fp8_f32(v.z, v.w, w, true);
    return (unsigned)w;
}
#else
__device__ inline float fp8_to_f32_1(unsigned b) {
    unsigned s = (b & 0x80u) << 24;
    unsigned em = b & 0x7fu;
    float f;
    if (em >= 8) f = __uint_as_float((em << 20) + (120u << 23));
    else f = (float)em * 0.001953125f;
    return __uint_as_float(__float_as_uint(f) | s);
}
__device__ inline f32x2 fp8pk_lo(unsigned u) {
    f32x2 r;
    r[0] = fp8_to_f32_1(u & 0xffu);
    r[1] = fp8_to_f32_1((u >> 8) & 0xffu);
    return r;
}
__device__ inline f32x2 fp8pk_hi(unsigned u) {
    f32x2 r;
    r[0] = fp8_to_f32_1((u >> 16) & 0xffu);
    r[1] = fp8_to_f32_1((u >> 24) & 0xffu);
    return r;
}
__device__ inline unsigned f32_to_fp8_1(float f) {
    unsigned s = (__float_as_uint(f) >> 24) & 0x80u;
    float a = fabsf(f);
    if (!(a > 0.f)) return s;
    if (a >= 448.f) return s | 0x7Eu;
    int e = (int)(__float_as_uint(a) >> 23) - 127;
    if (e < -6) e = -6;
    float step = __uint_as_float((unsigned)(e - 3 + 127) << 23);
    int m = (int)rintf(a / step);
    if (m >= 16) { e += 1; m = 8; }
    if (m >= 8) return s | (unsigned)((e + 7) << 3) | (unsigned)(m - 8);
    return s | (unsigned)m;
}
__device__ inline unsigned f32x4_to_fp8(float4 v) {
    return f32_to_fp8_1(v.x) | (f32_to_fp8_1(v.y) << 8) |
           (f32_to_fp8_1(v.z) << 16) | (f32_to_fp8_1(v.w) << 24);
}
#endif

// accumulate 8 fp8 features from a uint2 into 4 packed f32x2 accumulators
#define ACC8(u)                                                              \
    {                                                                        \
        aa0 += fp8pk_lo((u).x);                                              \
        aa1 += fp8pk_hi((u).x);                                              \
        aa2 += fp8pk_lo((u).y);                                              \
        aa3 += fp8pk_hi((u).y);                                              \
    }

// Detect whether edge_index arrived as int64 (odd int32 words all zero).
__global__ void k_detect(const int* __restrict__ ei, int* __restrict__ flag) {
    int lane = threadIdx.x;
    int v = ei[2 * lane + 1];
    unsigned long long b = __ballot(v == 0);
    if (lane == 0) *flag = (b == ~0ull) ? 1 : 0;
}

// Build bf16 copy (GEMM), fp8 copy (gather), and transposed bf16 W, one kernel.
__global__ __launch_bounds__(256) void k_prep(const float* __restrict__ x,
                                              unsigned* __restrict__ xb,
                                              unsigned* __restrict__ xq,
                                              const float* __restrict__ Wl,
                                              const float* __restrict__ Wr,
                                              unsigned short* __restrict__ Wt) {
    int bid = blockIdx.x;
    if (bid < 2048) {
        int total = NN * DD / 4;
        for (int i = bid * 256 + threadIdx.x; i < total; i += 2048 * 256) {
            float4 v = ((const float4*)x)[i];
            unsigned a = (bf16rne(v.y) << 16) | bf16rne(v.x);
            unsigned b = (bf16rne(v.w) << 16) | bf16rne(v.z);
            ((uint2*)xb)[i] = make_uint2(a, b);
            xq[i] = f32x4_to_fp8(v);
        }
    } else {
        int idx = (bid - 2048) * 256 + threadIdx.x;   // 32768 total
        int n = idx >> 8, k = idx & 255;
        float v = (k < 128) ? Wl[(size_t)k * DD + n] : Wr[(size_t)(k - 128) * DD + n];
        Wt[idx] = (unsigned short)bf16rne(v);
    }
}

// Coarse bucket histogram (782 buckets) via block-LDS hist + one flush.
__global__ __launch_bounds__(256) void k_bcount(const int* __restrict__ ei,
                                                const int* __restrict__ flag,
                                                int* __restrict__ cnt) {
    __shared__ int hist[NB];
    for (int i = threadIdx.x; i < NB; i += 256) hist[i] = 0;
    __syncthreads();
    int i64 = *flag;
    int stride = gridDim.x * 256;
    for (int e = blockIdx.x * 256 + threadIdx.x; e < NE; e += stride) {
        int dst = i64 ? ei[2 * (NE + e)] : ei[NE + e];
        atomicAdd(&hist[dst >> 7], 1);
    }
    __syncthreads();
    for (int i = threadIdx.x; i < NB; i += 256) {
        int c = hist[i];
        if (c) atomicAdd(&cnt[i], c);
    }
}

// Exclusive scan of the 782 bucket counts.
__global__ __launch_bounds__(256) void k_scan(const int* __restrict__ cnt,
                                              int* __restrict__ coff,
                                              int* __restrict__ cur) {
    __shared__ int s[NB];
    for (int i = threadIdx.x; i < NB; i += 256) s[i] = cnt[i];
    __syncthreads();
    if (threadIdx.x == 0) {
        int acc = 0;
        for (int i = 0; i < NB; ++i) { int c = s[i]; s[i] = acc; acc += c; }
    }
    __syncthreads();
    for (int i = threadIdx.x; i < NB; i += 256) { coff[i] = s[i]; cur[i] = s[i]; }
    if (threadIdx.x == 0) coff[NB] = NE;
}

// Bin edges by coarse bucket. In-LDS bucket-sort of edge indices, then a
// COALESCED flush.
__global__ __launch_bounds__(256) void k_bin(const int* __restrict__ ei,
                                             const int* __restrict__ flag,
                                             int* __restrict__ cur,
                                             unsigned* __restrict__ bin) {
    __shared__ int hist[NB];
    __shared__ int sbs[NB];
    __shared__ int gbase[NB];
    __shared__ int rk[NB];
    __shared__ int wsum[256];
    __shared__ unsigned short sj[RND];
    int tid = threadIdx.x;
    for (int i = tid; i < NB; i += 256) { hist[i] = 0; rk[i] = 0; }
    __syncthreads();
    int i64 = *flag;
    int e0 = blockIdx.x * RND;
    int cntE = NE - e0; if (cntE > RND) cntE = RND;

    for (int j = tid; j < cntE; j += 256) {
        int e = e0 + j;
        int dst = i64 ? ei[2 * (NE + e)] : ei[NE + e];
        atomicAdd(&hist[dst >> 7], 1);
    }
    __syncthreads();

    int b4 = tid * 4;
    int l0 = (b4 + 0 < NB) ? hist[b4 + 0] : 0;
    int l1 = (b4 + 1 < NB) ? hist[b4 + 1] : 0;
    int l2 = (b4 + 2 < NB) ? hist[b4 + 2] : 0;
    int l3 = (b4 + 3 < NB) ? hist[b4 + 3] : 0;
    int tsum = l0 + l1 + l2 + l3;
    wsum[tid] = tsum;
    __syncthreads();
    for (int d = 1; d < 256; d <<= 1) {
        int v = (tid >= d) ? wsum[tid - d] : 0;
        __syncthreads();
        wsum[tid] += v;
        __syncthreads();
    }
    int p = wsum[tid] - tsum;
    if (b4 + 0 < NB) sbs[b4 + 0] = p;
    if (b4 + 1 < NB) sbs[b4 + 1] = p + l0;
    if (b4 + 2 < NB) sbs[b4 + 2] = p + l0 + l1;
    if (b4 + 3 < NB) sbs[b4 + 3] = p + l0 + l1 + l2;
    __syncthreads();

    for (int j = tid; j < cntE; j += 256) {
        int e = e0 + j;
        int dst = i64 ? ei[2 * (NE + e)] : ei[NE + e];
        int b = dst >> 7;
        int r = atomicAdd(&rk[b], 1);
        sj[sbs[b] + r] = (unsigned short)j;
    }
    for (int b = tid; b < NB; b += 256) {
        int c = hist[b];
        if (c > 0) gbase[b] = atomicAdd(&cur[b], c);
    }
    __syncthreads();

    for (int t = tid; t < cntE; t += 256) {
        int j = sj[t];
        int e = e0 + j;
        int src = i64 ? ei[2 * e] : ei[e];
        int dst = i64 ? ei[2 * (NE + e)] : ei[NE + e];
        int b = dst >> 7;
        bin[gbase[b] + (t - sbs[b])] = ((unsigned)src << 7) | (unsigned)(dst & 127);
    }
}

// Per-bucket counting sort -> node-grouped CSR + deg/off.
__global__ __launch_bounds__(256) void k_csr(const unsigned* __restrict__ bin,
                                             const int* __restrict__ coff,
                                             int* __restrict__ csr,
                                             int* __restrict__ deg,
                                             int* __restrict__ off) {
    __shared__ int hist[128];
    __shared__ int sb[128];
    __shared__ int curs[128];
    int b = blockIdx.x;
    int tid = threadIdx.x;
    if (tid < 128) hist[tid] = 0;
    __syncthreads();
    int e0 = coff[b], e1 = coff[b + 1];
    for (int j = e0 + tid; j < e1; j += 256)
        atomicAdd(&hist[bin[j] & 127], 1);
    __syncthreads();
    if (tid == 0) {
        int acc = 0;
        for (int i = 0; i < 128; ++i) { sb[i] = acc; acc += hist[i]; }
    }
    __syncthreads();
    if (tid < 128) curs[tid] = sb[tid];
    __syncthreads();
    for (int j = e0 + tid; j < e1; j += 256) {
        unsigned p = bin[j];
        int d = p & 127;
        int r = atomicAdd(&curs[d], 1);
        csr[e0 + r] = (int)(p >> 7);
    }
    int n = b * 128 + tid;
    if (tid < 128 && n < NN) {
        deg[n] = hist[tid];
        off[n] = e0 + sb[tid];
    }
}

// Wave-per-node gather-sum from the fp8 copy, 4 rows per wave-load,
// packed f32x2 accumulate.
__global__ __launch_bounds__(256) void k_agg(const uint2* __restrict__ xq2,
                                             const int* __restrict__ csr,
                                             const int* __restrict__ deg,
                                             const int* __restrict__ off,
                                             unsigned* __restrict__ aggb) {
    int w = (blockIdx.x * 256 + threadIdx.x) >> 6;
    int lane = threadIdx.x & 63;
    if (w >= NN) return;
    int dg = deg[w];
    int o = off[w];
    int q = lane >> 4;       // edge sub-slot (0..3)
    int cl = lane & 15;      // uint2 slot within the 128B row
    f32x2 aa0 = {0.f, 0.f}, aa1 = {0.f, 0.f}, aa2 = {0.f, 0.f}, aa3 = {0.f, 0.f};

    int j = 0;
    for (; j + 16 <= dg; j += 16) {
        int s0 = csr[o + j + q];
        int s1 = csr[o + j + 4 + q];
        int s2 = csr[o + j + 8 + q];
        int s3 = csr[o + j + 12 + q];
        uint2 u0 = xq2[(size_t)s0 * 16 + cl];
        uint2 u1 = xq2[(size_t)s1 * 16 + cl];
        uint2 u2 = xq2[(size_t)s2 * 16 + cl];
        uint2 u3 = xq2[(size_t)s3 * 16 + cl];
        ACC8(u0); ACC8(u1); ACC8(u2); ACC8(u3);
    }
    for (; j + 4 <= dg; j += 4) {
        int s = csr[o + j + q];
        uint2 u = xq2[(size_t)s * 16 + cl];
        ACC8(u);
    }
    int rem = dg - j;        // 0..3
    if (q < rem) {
        int s = csr[o + j + q];
        uint2 u = xq2[(size_t)s * 16 + cl];
        ACC8(u);
    }

    float a0 = aa0[0], a1 = aa0[1], a2 = aa1[0], a3 = aa1[1];
    float a4 = aa2[0], a5 = aa2[1], a6 = aa3[0], a7 = aa3[1];
    a0 += __shfl_xor(a0, 16); a0 += __shfl_xor(a0, 32);
    a1 += __shfl_xor(a1, 16); a1 += __shfl_xor(a1, 32);
    a2 += __shfl_xor(a2, 16); a2 += __shfl_xor(a2, 32);
    a3 += __shfl_xor(a3, 16); a3 += __shfl_xor(a3, 32);
    a4 += __shfl_xor(a4, 16); a4 += __shfl_xor(a4, 32);
    a5 += __shfl_xor(a5, 16); a5 += __shfl_xor(a5, 32);
    a6 += __shfl_xor(a6, 16); a6 += __shfl_xor(a6, 32);
    a7 += __shfl_xor(a7, 16); a7 += __shfl_xor(a7, 32);

    if (lane < 16) {
        float inv = 1.0f / fmaxf((float)dg, 1.0f);
        uint4 p;
        p.x = (bf16rne(a1 * inv) << 16) | bf16rne(a0 * inv);
        p.y = (bf16rne(a3 * inv) << 16) | bf16rne(a2 * inv);
        p.z = (bf16rne(a5 * inv) << 16) | bf16rne(a4 * inv);
        p.w = (bf16rne(a7 * inv) << 16) | bf16rne(a6 * inv);
        ((uint4*)aggb)[(size_t)w * 16 + cl] = p;
    }
}

// MFMA GEMM: x_raw = [agg | x]_bf16 @ Wt^T + b, BN stats fused into epilogue.
// Round-14 shape (wave = 32 rows x 128 cols, 782 blocks) + Wt staged in LDS
// with 528B padded row stride (8-bank spread -> 2-way conflict, free).
// Inner loop: only the 16 A-loads are long-latency; Wt comes from LDS.
__global__ __launch_bounds__(256) void k_gemm(const unsigned short* __restrict__ aggb,
                                              const unsigned short* __restrict__ xb,
                                              const unsigned short* __restrict__ Wt,
                                              const float* __restrict__ bl,
                                              float* __restrict__ out_raw,
                                              float* __restrict__ bn_sum,
                                              float* __restrict__ bn_sq) {
    __shared__ unsigned short sW[128][264];   // 67.6 KB, stride 528B
    __shared__ float s_s[4][128];
    __shared__ float s_q[4][128];
    int tid = threadIdx.x;
    int wv = tid >> 6, lane = tid & 63;
    int l15 = lane & 15, lhi = lane >> 4;
    int mr = blockIdx.x * 128 + wv * 32;

    // stage Wt (64KB) into LDS: 4096 uint4 chunks, linear rows
    {
        const uint4* g = (const uint4*)Wt;
        #pragma unroll
        for (int it = 0; it < 16; ++it) {
            int c = tid + it * 256;
            int row = c >> 5;             // c/32 (32 chunks of 8 ushorts per 256-row)
            int col = (c & 31) * 8;
            *(uint4*)&sW[row][col] = g[c];
        }
    }

    int r0 = mr + l15;       if (r0 > NN - 1) r0 = NN - 1;
    int r1 = mr + 16 + l15;  if (r1 > NN - 1) r1 = NN - 1;
    const unsigned short* a0p = aggb + (size_t)r0 * DD;
    const unsigned short* a1p = aggb + (size_t)r1 * DD;
    const unsigned short* x0p = xb + (size_t)r0 * DD;
    const unsigned short* x1p = xb + (size_t)r1 * DD;

    f32x4 acc[2][8];
    #pragma unroll
    for (int m = 0; m < 2; ++m)
        #pragma unroll
        for (int nt = 0; nt < 8; ++nt)
            acc[m][nt] = (f32x4){0.f, 0.f, 0.f, 0.f};

    __syncthreads();

    #pragma unroll
    for (int ks = 0; ks < 8; ++ks) {
        int kk = (ks & 3) * 32 + lhi * 8;
        bf16x8 a0, a1;
        if (ks < 4) {
            a0 = *(const bf16x8*)(a0p + kk);
            a1 = *(const bf16x8*)(a1p + kk);
        } else {
            a0 = *(const bf16x8*)(x0p + kk);
            a1 = *(const bf16x8*)(x1p + kk);
        }
        #pragma unroll
        for (int nt = 0; nt < 8; ++nt) {
            bf16x8 b = *(const bf16x8*)&sW[nt * 16 + l15][ks * 32 + lhi * 8];
            acc[0][nt] = __builtin_amdgcn_mfma_f32_16x16x32_bf16(a0, b, acc[0][nt], 0, 0, 0);
            acc[1][nt] = __builtin_amdgcn_mfma_f32_16x16x32_bf16(a1, b, acc[1][nt], 0, 0, 0);
        }
    }

    // epilogue: bias + store (D layout: row=lhi*4+reg, col=l15) + column stats
    float bias8[8];
    #pragma unroll
    for (int nt = 0; nt < 8; ++nt) bias8[nt] = bl[nt * 16 + l15];

    float s8[8] = {}, q8[8] = {};
    #pragma unroll
    for (int m = 0; m < 2; ++m) {
        #pragma unroll
        for (int r = 0; r < 4; ++r) {
            int row = mr + m * 16 + lhi * 4 + r;
            if (row < NN) {
                #pragma unroll
                for (int nt = 0; nt < 8; ++nt) {
                    float v = acc[m][nt][r] + bias8[nt];
                    out_raw[(size_t)row * DD + nt * 16 + l15] = v;
                    s8[nt] += v;
                    q8[nt] += v * v;
                }
            }
        }
    }

    #pragma unroll
    for (int nt = 0; nt < 8; ++nt) {
        s8[nt] += __shfl_xor(s8[nt], 16);
        s8[nt] += __shfl_xor(s8[nt], 32);
        q8[nt] += __shfl_xor(q8[nt], 16);
        q8[nt] += __shfl_xor(q8[nt], 32);
    }
    if (lhi == 0) {
        #pragma unroll
        for (int nt = 0; nt < 8; ++nt) {
            s_s[wv][nt * 16 + l15] = s8[nt];
            s_q[wv][nt * 16 + l15] = q8[nt];
        }
    }
    __syncthreads();
    if (tid < 128) {
        float ts = s_s[0][tid] + s_s[1][tid] + s_s[2][tid] + s_s[3][tid];
        float tq = s_q[0][tid] + s_q[1][tid] + s_q[2][tid] + s_q[3][tid];
        atomicAdd(&bn_sum[tid], ts);
        atomicAdd(&bn_sq[tid], tq);
    }
}

__global__ __launch_bounds__(256) void k_norm(const float* __restrict__ raw,
                                              const float* __restrict__ bn_sum,
                                              const float* __restrict__ bn_sq,
                                              const float* __restrict__ gamma,
                                              const float* __restrict__ beta,
                                              float* __restrict__ out) {
    const float invN = 1.0f / (float)NN;
    int total = NN * DD / 4;
    for (int idx = blockIdx.x * 256 + threadIdx.x; idx < total; idx += gridDim.x * 256) {
        int cp = idx & 31;
        float4 v = ((const float4*)raw)[idx];
        float4 s = ((const float4*)bn_sum)[cp];
        float4 q = ((const float4*)bn_sq)[cp];
        float4 g = ((const float4*)gamma)[cp];
        float4 b = ((const float4*)beta)[cp];
        float4 o;
        { float mu = s.x * invN; float var = q.x * invN - mu * mu;
          o.x = (v.x - mu) * rsqrtf(var + BN_EPS) * g.x + b.x; }
        { float mu = s.y * invN; float var = q.y * invN - mu * mu;
          o.y = (v.y - mu) * rsqrtf(var + BN_EPS) * g.y + b.y; }
        { float mu = s.z * invN; float var = q.z * invN - mu * mu;
          o.z = (v.z - mu) * rsqrtf(var + BN_EPS) * g.z + b.z; }
        { float mu = s.w * invN; float var = q.w * invN - mu * mu;
          o.w = (v.w - mu) * rsqrtf(var + BN_EPS) * g.w + b.w; }
        ((float4*)out)[idx] = o;
    }
}

extern "C" void kernel_launch(void* const* d_in, const int* in_sizes, int n_in,
                              void* d_out, int out_size, void* d_ws, size_t ws_size,
                              hipStream_t stream) {
    const float* x     = (const float*)d_in[0];
    const int*   ei    = (const int*)d_in[1];
    const float* Wl    = (const float*)d_in[2];
    const float* bl    = (const float*)d_in[3];
    const float* Wr    = (const float*)d_in[4];
    const float* gamma = (const float*)d_in[5];
    const float* beta  = (const float*)d_in[6];

    float* out_raw = (float*)d_out;                       // [NN][DD] x_raw
    float* out_bn  = out_raw + (size_t)NN * DD;           // [NN][DD] x_deskewed
    unsigned* xq   = (unsigned*)d_out;                    // fp8[NN*128] in out_raw half
    unsigned* bin  = (unsigned*)out_bn;                   // uint[NE]
    unsigned* aggb = (unsigned*)out_bn;                   // bf16[NN*128] packed
    unsigned* xb   = (unsigned*)((char*)out_bn + (size_t)NN * DD * 2); // bf16[NN*128]

    char* ws = (char*)d_ws;
    int*   cnt    = (int*)(ws + WS_CNT);
    int*   coff   = (int*)(ws + WS_COFF);
    int*   cur    = (int*)(ws + WS_CUR);
    int*   flag   = (int*)(ws + WS_FLAG);
    float* bn_sum = (float*)(ws + WS_BNSUM);
    float* bn_sq  = (float*)(ws + WS_BNSQ);
    int*   deg    = (int*)(ws + WS_DEG);
    int*   off    = (int*)(ws + WS_OFF);
    int*   csr    = (int*)(ws + WS_CSR);
    unsigned short* Wt = (unsigned short*)(ws + WS_WT);

    hipMemsetAsync(d_ws, 0, WS_ZERO, stream);

    k_detect<<<1, 64, 0, stream>>>(ei, flag);
    k_prep<<<2048 + 128, 256, 0, stream>>>(x, xb, xq, Wl, Wr, Wt);
    k_bcount<<<512, 256, 0, stream>>>(ei, flag, cnt);
    k_scan<<<1, 256, 0, stream>>>(cnt, coff, cur);
    k_bin<<<(NE + RND - 1) / RND, 256, 0, stream>>>(ei, flag, cur, bin);
    k_csr<<<NB, 256, 0, stream>>>(bin, coff, csr, deg, off);
    k_agg<<<(NN * 64 + 255) / 256, 256, 0, stream>>>((const uint2*)xq, csr, deg, off, aggb);
    k_gemm<<<(NN + 127) / 128, 256, 0, stream>>>((const unsigned short*)aggb,
                                                 (const unsigned short*)xb,
                                                 Wt, bl, out_raw, bn_sum, bn_sq);
    k_norm<<<4096, 256, 0, stream>>>(out_raw, bn_sum, bn_sq, gamma, beta, out_bn);
}

// Round 18
// 225.711 us; speedup vs baseline: 1.2336x; 1.0100x over previous
//
#include <hip/hip_runtime.h>

constexpr int NN = 100000;
constexpr int NE = 3200000;
constexpr int DD = 128;
constexpr int NB = 782;          // ceil(NN/128) buckets of 128 nodes
constexpr int RND = 8192;        // edges binned per block (391 blocks)
#define BN_EPS 1e-5f

typedef __attribute__((ext_vector_type(8))) short bf16x8;
typedef __attribute__((ext_vector_type(4))) float f32x4;
typedef __attribute__((ext_vector_type(2))) float f32x2;

// ---- workspace layout (bytes) ----
constexpr size_t WS_CNT   = 0;            // int[NB]
constexpr size_t WS_COFF  = 4096;         // int[NB+1]
constexpr size_t WS_CUR   = 8192;         // int[NB]
constexpr size_t WS_FLAG  = 12288;        // int[1]
constexpr size_t WS_BNSUM = 12800;        // float[128]
constexpr size_t WS_BNSQ  = 13312;        // float[128]
constexpr size_t WS_ZERO  = 16384;        // memset range
constexpr size_t WS_DEG   = 16384;        // int[NN]
constexpr size_t WS_OFF   = 416384;       // int[NN]
constexpr size_t WS_CSR   = 816384;       // int[NE]
constexpr size_t WS_WT    = 13616384;     // ushort[128*256] transposed bf16 W (64KB)
// d_out first half (out_raw): xq (fp8[NN*128], 12.8MB) at offset 0, dead after
//   k_agg; k_gemm overwrites with x_raw.
// d_out second half (out_bn): bin (uint[NE]) at [0,12.8M) until k_csr;
//   aggb (bf16[NN*128]) at [0,25.6M) from k_agg; xb (bf16[NN*128]) at [25.6M,51.2M).
//   All dead before k_norm writes x_deskewed.

__device__ inline unsigned bf16rne(float f) {
    unsigned u = __float_as_uint(f);
    return (u + 0x7fffu + ((u >> 16) & 1u)) >> 16;
}

#if __has_builtin(__builtin_amdgcn_cvt_pk_f32_fp8)
__device__ inline f32x2 fp8pk_lo(unsigned u) {
    return __builtin_amdgcn_cvt_pk_f32_fp8((int)u, false);
}
__device__ inline f32x2 fp8pk_hi(unsigned u) {
    return __builtin_amdgcn_cvt_pk_f32_fp8((int)u, true);
}
__device__ inline unsigned f32x4_to_fp8(float4 v) {
    int w = __builtin_amdgcn_cvt_pk_fp8_f32(v.x, v.y, 0, false);
    w = __builtin_amdgcn_cvt_pk_fp8_f32(v.z, v.w, w, true);
    return (unsigned)w;
}
#else
__device__ inline float fp8_to_f32_1(unsigned b) {
    unsigned s = (b & 0x80u) << 24;
    unsigned em = b & 0x7fu;
    float f;
    if (em >= 8) f = __uint_as_float((em << 20) + (120u << 23));
    else f = (float)em * 0.001953125f;
    return __uint_as_float(__float_as_uint(f) | s);
}
__device__ inline f32x2 fp8pk_lo(unsigned u) {
    f32x2 r;
    r[0] = fp8_to_f32_1(u & 0xffu);
    r[1] = fp8_to_f32_1((u >> 8) & 0xffu);
    return r;
}
__device__ inline f32x2 fp8pk_hi(unsigned u) {
    f32x2 r;
    r[0] = fp8_to_f32_1((u >> 16) & 0xffu);
    r[1] = fp8_to_f32_1((u >> 24) & 0xffu);
    return r;
}
__device__ inline unsigned f32_to_fp8_1(float f) {
    unsigned s = (__float_as_uint(f) >> 24) & 0x80u;
    float a = fabsf(f);
    if (!(a > 0.f)) return s;
    if (a >= 448.f) return s | 0x7Eu;
    int e = (int)(__float_as_uint(a) >> 23) - 127;
    if (e < -6) e = -6;
    float step = __uint_as_float((unsigned)(e - 3 + 127) << 23);
    int m = (int)rintf(a / step);
    if (m >= 16) { e += 1; m = 8; }
    if (m >= 8) return s | (unsigned)((e + 7) << 3) | (unsigned)(m - 8);
    return s | (unsigned)m;
}
__device__ inline unsigned f32x4_to_fp8(float4 v) {
    return f32_to_fp8_1(v.x) | (f32_to_fp8_1(v.y) << 8) |
           (f32_to_fp8_1(v.z) << 16) | (f32_to_fp8_1(v.w) << 24);
}
#endif

// accumulate 8 fp8 features from a uint2 into 4 packed f32x2 accumulators
#define ACC8(u)                                                              \
    {                                                                        \
        aa0 += fp8pk_lo((u).x);                                              \
        aa1 += fp8pk_hi((u).x);                                              \
        aa2 += fp8pk_lo((u).y);                                              \
        aa3 += fp8pk_hi((u).y);                                              \
    }

// Detect whether edge_index arrived as int64 (odd int32 words all zero).
__global__ void k_detect(const int* __restrict__ ei, int* __restrict__ flag) {
    int lane = threadIdx.x;
    int v = ei[2 * lane + 1];
    unsigned long long b = __ballot(v == 0);
    if (lane == 0) *flag = (b == ~0ull) ? 1 : 0;
}

// Build bf16 copy (GEMM), fp8 copy (gather), and transposed bf16 W, one kernel.
__global__ __launch_bounds__(256) void k_prep(const float* __restrict__ x,
                                              unsigned* __restrict__ xb,
                                              unsigned* __restrict__ xq,
                                              const float* __restrict__ Wl,
                                              const float* __restrict__ Wr,
                                              unsigned short* __restrict__ Wt) {
    int bid = blockIdx.x;
    if (bid < 2048) {
        int total = NN * DD / 4;
        for (int i = bid * 256 + threadIdx.x; i < total; i += 2048 * 256) {
            float4 v = ((const float4*)x)[i];
            unsigned a = (bf16rne(v.y) << 16) | bf16rne(v.x);
            unsigned b = (bf16rne(v.w) << 16) | bf16rne(v.z);
            ((uint2*)xb)[i] = make_uint2(a, b);
            xq[i] = f32x4_to_fp8(v);
        }
    } else {
        int idx = (bid - 2048) * 256 + threadIdx.x;   // 32768 total
        int n = idx >> 8, k = idx & 255;
        float v = (k < 128) ? Wl[(size_t)k * DD + n] : Wr[(size_t)(k - 128) * DD + n];
        Wt[idx] = (unsigned short)bf16rne(v);
    }
}

// Coarse bucket histogram via block-LDS hist + one flush. Vectorized dst
// loads: int4 per thread = 2 edges (i64 layout) or 4 edges (i32 layout).
__global__ __launch_bounds__(256) void k_bcount(const int* __restrict__ ei,
                                                const int* __restrict__ flag,
                                                int* __restrict__ cnt) {
    __shared__ int hist[NB];
    for (int i = threadIdx.x; i < NB; i += 256) hist[i] = 0;
    __syncthreads();
    int i64 = *flag;
    int stride = gridDim.x * 256;
    if (i64) {
        const int4* dp = (const int4*)(ei + 2 * (size_t)NE);
        int total = NE / 2;
        for (int i = blockIdx.x * 256 + threadIdx.x; i < total; i += stride) {
            int4 v = dp[i];
            atomicAdd(&hist[v.x >> 7], 1);
            atomicAdd(&hist[v.z >> 7], 1);
        }
    } else {
        const int4* dp = (const int4*)(ei + (size_t)NE);
        int total = NE / 4;
        for (int i = blockIdx.x * 256 + threadIdx.x; i < total; i += stride) {
            int4 v = dp[i];
            atomicAdd(&hist[v.x >> 7], 1);
            atomicAdd(&hist[v.y >> 7], 1);
            atomicAdd(&hist[v.z >> 7], 1);
            atomicAdd(&hist[v.w >> 7], 1);
        }
    }
    __syncthreads();
    for (int i = threadIdx.x; i < NB; i += 256) {
        int c = hist[i];
        if (c) atomicAdd(&cnt[i], c);
    }
}

// Exclusive scan of the 782 bucket counts.
__global__ __launch_bounds__(256) void k_scan(const int* __restrict__ cnt,
                                              int* __restrict__ coff,
                                              int* __restrict__ cur) {
    __shared__ int s[NB];
    for (int i = threadIdx.x; i < NB; i += 256) s[i] = cnt[i];
    __syncthreads();
    if (threadIdx.x == 0) {
        int acc = 0;
        for (int i = 0; i < NB; ++i) { int c = s[i]; s[i] = acc; acc += c; }
    }
    __syncthreads();
    for (int i = threadIdx.x; i < NB; i += 256) { coff[i] = s[i]; cur[i] = s[i]; }
    if (threadIdx.x == 0) coff[NB] = NE;
}

// Bin edges by coarse bucket. In-LDS bucket-sort of edge indices, then a
// COALESCED flush.
__global__ __launch_bounds__(256) void k_bin(const int* __restrict__ ei,
                                             const int* __restrict__ flag,
                                             int* __restrict__ cur,
                                             unsigned* __restrict__ bin) {
    __shared__ int hist[NB];
    __shared__ int sbs[NB];
    __shared__ int gbase[NB];
    __shared__ int rk[NB];
    __shared__ int wsum[256];
    __shared__ unsigned short sj[RND];
    int tid = threadIdx.x;
    for (int i = tid; i < NB; i += 256) { hist[i] = 0; rk[i] = 0; }
    __syncthreads();
    int i64 = *flag;
    int e0 = blockIdx.x * RND;
    int cntE = NE - e0; if (cntE > RND) cntE = RND;

    for (int j = tid; j < cntE; j += 256) {
        int e = e0 + j;
        int dst = i64 ? ei[2 * (NE + e)] : ei[NE + e];
        atomicAdd(&hist[dst >> 7], 1);
    }
    __syncthreads();

    int b4 = tid * 4;
    int l0 = (b4 + 0 < NB) ? hist[b4 + 0] : 0;
    int l1 = (b4 + 1 < NB) ? hist[b4 + 1] : 0;
    int l2 = (b4 + 2 < NB) ? hist[b4 + 2] : 0;
    int l3 = (b4 + 3 < NB) ? hist[b4 + 3] : 0;
    int tsum = l0 + l1 + l2 + l3;
    wsum[tid] = tsum;
    __syncthreads();
    for (int d = 1; d < 256; d <<= 1) {
        int v = (tid >= d) ? wsum[tid - d] : 0;
        __syncthreads();
        wsum[tid] += v;
        __syncthreads();
    }
    int p = wsum[tid] - tsum;
    if (b4 + 0 < NB) sbs[b4 + 0] = p;
    if (b4 + 1 < NB) sbs[b4 + 1] = p + l0;
    if (b4 + 2 < NB) sbs[b4 + 2] = p + l0 + l1;
    if (b4 + 3 < NB) sbs[b4 + 3] = p + l0 + l1 + l2;
    __syncthreads();

    for (int j = tid; j < cntE; j += 256) {
        int e = e0 + j;
        int dst = i64 ? ei[2 * (NE + e)] : ei[NE + e];
        int b = dst >> 7;
        int r = atomicAdd(&rk[b], 1);
        sj[sbs[b] + r] = (unsigned short)j;
    }
    for (int b = tid; b < NB; b += 256) {
        int c = hist[b];
        if (c > 0) gbase[b] = atomicAdd(&cur[b], c);
    }
    __syncthreads();

    for (int t = tid; t < cntE; t += 256) {
        int j = sj[t];
        int e = e0 + j;
        int src = i64 ? ei[2 * e] : ei[e];
        int dst = i64 ? ei[2 * (NE + e)] : ei[NE + e];
        int b = dst >> 7;
        bin[gbase[b] + (t - sbs[b])] = ((unsigned)src << 7) | (unsigned)(dst & 127);
    }
}

// Per-bucket counting sort -> node-grouped CSR (PRE-SCALED src*16 for k_agg's
// uint2 addressing) + deg/off.
__global__ __launch_bounds__(256) void k_csr(const unsigned* __restrict__ bin,
                                             const int* __restrict__ coff,
                                             int* __restrict__ csr,
                                             int* __restrict__ deg,
                                             int* __restrict__ off) {
    __shared__ int hist[128];
    __shared__ int sb[128];
    __shared__ int curs[128];
    int b = blockIdx.x;
    int tid = threadIdx.x;
    if (tid < 128) hist[tid] = 0;
    __syncthreads();
    int e0 = coff[b], e1 = coff[b + 1];
    for (int j = e0 + tid; j < e1; j += 256)
        atomicAdd(&hist[bin[j] & 127], 1);
    __syncthreads();
    if (tid == 0) {
        int acc = 0;
        for (int i = 0; i < 128; ++i) { sb[i] = acc; acc += hist[i]; }
    }
    __syncthreads();
    if (tid < 128) curs[tid] = sb[tid];
    __syncthreads();
    for (int j = e0 + tid; j < e1; j += 256) {
        unsigned p = bin[j];
        int d = p & 127;
        int r = atomicAdd(&curs[d], 1);
        csr[e0 + r] = (int)((p >> 7) << 4);   // src * 16 (uint2-row base)
    }
    int n = b * 128 + tid;
    if (tid < 128 && n < NN) {
        deg[n] = hist[tid];
        off[n] = e0 + sb[tid];
    }
}

// Wave-per-node gather-sum from the fp8 copy, 4 rows per wave-load,
// packed f32x2 accumulate. csr is pre-scaled (src*16): address = csrval + cl.
__global__ __launch_bounds__(256) void k_agg(const uint2* __restrict__ xq2,
                                             const int* __restrict__ csr,
                                             const int* __restrict__ deg,
                                             const int* __restrict__ off,
                                             unsigned* __restrict__ aggb) {
    int w = (blockIdx.x * 256 + threadIdx.x) >> 6;
    int lane = threadIdx.x & 63;
    if (w >= NN) return;
    int dg = deg[w];
    int o = off[w];
    int q = lane >> 4;       // edge sub-slot (0..3)
    int cl = lane & 15;      // uint2 slot within the 128B row
    const uint2* xp = xq2 + cl;
    f32x2 aa0 = {0.f, 0.f}, aa1 = {0.f, 0.f}, aa2 = {0.f, 0.f}, aa3 = {0.f, 0.f};

    int j = 0;
    for (; j + 16 <= dg; j += 16) {
        int s0 = csr[o + j + q];
        int s1 = csr[o + j + 4 + q];
        int s2 = csr[o + j + 8 + q];
        int s3 = csr[o + j + 12 + q];
        uint2 u0 = xp[s0];
        uint2 u1 = xp[s1];
        uint2 u2 = xp[s2];
        uint2 u3 = xp[s3];
        ACC8(u0); ACC8(u1); ACC8(u2); ACC8(u3);
    }
    for (; j + 4 <= dg; j += 4) {
        int s = csr[o + j + q];
        uint2 u = xp[s];
        ACC8(u);
    }
    int rem = dg - j;        // 0..3
    if (q < rem) {
        int s = csr[o + j + q];
        uint2 u = xp[s];
        ACC8(u);
    }

    float a0 = aa0[0], a1 = aa0[1], a2 = aa1[0], a3 = aa1[1];
    float a4 = aa2[0], a5 = aa2[1], a6 = aa3[0], a7 = aa3[1];
    a0 += __shfl_xor(a0, 16); a0 += __shfl_xor(a0, 32);
    a1 += __shfl_xor(a1, 16); a1 += __shfl_xor(a1, 32);
    a2 += __shfl_xor(a2, 16); a2 += __shfl_xor(a2, 32);
    a3 += __shfl_xor(a3, 16); a3 += __shfl_xor(a3, 32);
    a4 += __shfl_xor(a4, 16); a4 += __shfl_xor(a4, 32);
    a5 += __shfl_xor(a5, 16); a5 += __shfl_xor(a5, 32);
    a6 += __shfl_xor(a6, 16); a6 += __shfl_xor(a6, 32);
    a7 += __shfl_xor(a7, 16); a7 += __shfl_xor(a7, 32);

    if (lane < 16) {
        float inv = 1.0f / fmaxf((float)dg, 1.0f);
        uint4 p;
        p.x = (bf16rne(a1 * inv) << 16) | bf16rne(a0 * inv);
        p.y = (bf16rne(a3 * inv) << 16) | bf16rne(a2 * inv);
        p.z = (bf16rne(a5 * inv) << 16) | bf16rne(a4 * inv);
        p.w = (bf16rne(a7 * inv) << 16) | bf16rne(a6 * inv);
        ((uint4*)aggb)[(size_t)w * 16 + cl] = p;
    }
}

// MFMA GEMM: x_raw = [agg | x]_bf16 @ Wt^T + b, BN stats fused into epilogue.
// Wt staged in LDS (528B padded stride); ALL 16 A-fragments preloaded before
// the barrier (barrier's vmcnt(0) drain completes them at max MLP), so the
// MFMA loop is pure LDS + MFMA.
__global__ __launch_bounds__(256) void k_gemm(const unsigned short* __restrict__ aggb,
                                              const unsigned short* __restrict__ xb,
                                              const unsigned short* __restrict__ Wt,
                                              const float* __restrict__ bl,
                                              float* __restrict__ out_raw,
                                              float* __restrict__ bn_sum,
                                              float* __restrict__ bn_sq) {
    __shared__ unsigned short sW[128][264];   // 67.6 KB, stride 528B
    __shared__ float s_s[4][128];
    __shared__ float s_q[4][128];
    int tid = threadIdx.x;
    int wv = tid >> 6, lane = tid & 63;
    int l15 = lane & 15, lhi = lane >> 4;
    int mr = blockIdx.x * 128 + wv * 32;

    // stage Wt (64KB) into LDS
    {
        const uint4* g = (const uint4*)Wt;
        #pragma unroll
        for (int it = 0; it < 16; ++it) {
            int c = tid + it * 256;
            int row = c >> 5;
            int col = (c & 31) * 8;
            *(uint4*)&sW[row][col] = g[c];
        }
    }

    int r0 = mr + l15;       if (r0 > NN - 1) r0 = NN - 1;
    int r1 = mr + 16 + l15;  if (r1 > NN - 1) r1 = NN - 1;
    const unsigned short* a0p = aggb + (size_t)r0 * DD;
    const unsigned short* a1p = aggb + (size_t)r1 * DD;
    const unsigned short* x0p = xb + (size_t)r0 * DD;
    const unsigned short* x1p = xb + (size_t)r1 * DD;

    // preload all 16 A fragments (issued before the barrier -> 16 in flight)
    bf16x8 A0[8], A1[8];
    #pragma unroll
    for (int ks = 0; ks < 8; ++ks) {
        int kk = (ks & 3) * 32 + lhi * 8;
        if (ks < 4) {
            A0[ks] = *(const bf16x8*)(a0p + kk);
            A1[ks] = *(const bf16x8*)(a1p + kk);
        } else {
            A0[ks] = *(const bf16x8*)(x0p + kk);
            A1[ks] = *(const bf16x8*)(x1p + kk);
        }
    }

    f32x4 acc[2][8];
    #pragma unroll
    for (int m = 0; m < 2; ++m)
        #pragma unroll
        for (int nt = 0; nt < 8; ++nt)
            acc[m][nt] = (f32x4){0.f, 0.f, 0.f, 0.f};

    __syncthreads();

    #pragma unroll
    for (int ks = 0; ks < 8; ++ks) {
        #pragma unroll
        for (int nt = 0; nt < 8; ++nt) {
            bf16x8 b = *(const bf16x8*)&sW[nt * 16 + l15][ks * 32 + lhi * 8];
            acc[0][nt] = __builtin_amdgcn_mfma_f32_16x16x32_bf16(A0[ks], b, acc[0][nt], 0, 0, 0);
            acc[1][nt] = __builtin_amdgcn_mfma_f32_16x16x32_bf16(A1[ks], b, acc[1][nt], 0, 0, 0);
        }
    }

    // epilogue: bias + store (D layout: row=lhi*4+reg, col=l15) + column stats
    float bias8[8];
    #pragma unroll
    for (int nt = 0; nt < 8; ++nt) bias8[nt] = bl[nt * 16 + l15];

    float s8[8] = {}, q8[8] = {};
    #pragma unroll
    for (int m = 0; m < 2; ++m) {
        #pragma unroll
        for (int r = 0; r < 4; ++r) {
            int row = mr + m * 16 + lhi * 4 + r;
            if (row < NN) {
                #pragma unroll
                for (int nt = 0; nt < 8; ++nt) {
                    float v = acc[m][nt][r] + bias8[nt];
                    out_raw[(size_t)row * DD + nt * 16 + l15] = v;
                    s8[nt] += v;
                    q8[nt] += v * v;
                }
            }
        }
    }

    #pragma unroll
    for (int nt = 0; nt < 8; ++nt) {
        s8[nt] += __shfl_xor(s8[nt], 16);
        s8[nt] += __shfl_xor(s8[nt], 32);
        q8[nt] += __shfl_xor(q8[nt], 16);
        q8[nt] += __shfl_xor(q8[nt], 32);
    }
    if (lhi == 0) {
        #pragma unroll
        for (int nt = 0; nt < 8; ++nt) {
            s_s[wv][nt * 16 + l15] = s8[nt];
            s_q[wv][nt * 16 + l15] = q8[nt];
        }
    }
    __syncthreads();
    if (tid < 128) {
        float ts = s_s[0][tid] + s_s[1][tid] + s_s[2][tid] + s_s[3][tid];
        float tq = s_q[0][tid] + s_q[1][tid] + s_q[2][tid] + s_q[3][tid];
        atomicAdd(&bn_sum[tid], ts);
        atomicAdd(&bn_sq[tid], tq);
    }
}

__global__ __launch_bounds__(256) void k_norm(const float* __restrict__ raw,
                                              const float* __restrict__ bn_sum,
                                              const float* __restrict__ bn_sq,
                                              const float* __restrict__ gamma,
                                              const float* __restrict__ beta,
                                              float* __restrict__ out) {
    const float invN = 1.0f / (float)NN;
    int total = NN * DD / 4;
    for (int idx = blockIdx.x * 256 + threadIdx.x; idx < total; idx += gridDim.x * 256) {
        int cp = idx & 31;
        float4 v = ((const float4*)raw)[idx];
        float4 s = ((const float4*)bn_sum)[cp];
        float4 q = ((const float4*)bn_sq)[cp];
        float4 g = ((const float4*)gamma)[cp];
        float4 b = ((const float4*)beta)[cp];
        float4 o;
        { float mu = s.x * invN; float var = q.x * invN - mu * mu;
          o.x = (v.x - mu) * rsqrtf(var + BN_EPS) * g.x + b.x; }
        { float mu = s.y * invN; float var = q.y * invN - mu * mu;
          o.y = (v.y - mu) * rsqrtf(var + BN_EPS) * g.y + b.y; }
        { float mu = s.z * invN; float var = q.z * invN - mu * mu;
          o.z = (v.z - mu) * rsqrtf(var + BN_EPS) * g.z + b.z; }
        { float mu = s.w * invN; float var = q.w * invN - mu * mu;
          o.w = (v.w - mu) * rsqrtf(var + BN_EPS) * g.w + b.w; }
        ((float4*)out)[idx] = o;
    }
}

extern "C" void kernel_launch(void* const* d_in, const int* in_sizes, int n_in,
                              void* d_out, int out_size, void* d_ws, size_t ws_size,
                              hipStream_t stream) {
    const float* x     = (const float*)d_in[0];
    const int*   ei    = (const int*)d_in[1];
    const float* Wl    = (const float*)d_in[2];
    const float* bl    = (const float*)d_in[3];
    const float* Wr    = (const float*)d_in[4];
    const float* gamma = (const float*)d_in[5];
    const float* beta  = (const float*)d_in[6];

    float* out_raw = (float*)d_out;                       // [NN][DD] x_raw
    float* out_bn  = out_raw + (size_t)NN * DD;           // [NN][DD] x_deskewed
    unsigned* xq   = (unsigned*)d_out;                    // fp8[NN*128] in out_raw half
    unsigned* bin  = (unsigned*)out_bn;                   // uint[NE]
    unsigned* aggb = (unsigned*)out_bn;                   // bf16[NN*128] packed
    unsigned* xb   = (unsigned*)((char*)out_bn + (size_t)NN * DD * 2); // bf16[NN*128]

    char* ws = (char*)d_ws;
    int*   cnt    = (int*)(ws + WS_CNT);
    int*   coff   = (int*)(ws + WS_COFF);
    int*   cur    = (int*)(ws + WS_CUR);
    int*   flag   = (int*)(ws + WS_FLAG);
    float* bn_sum = (float*)(ws + WS_BNSUM);
    float* bn_sq  = (float*)(ws + WS_BNSQ);
    int*   deg    = (int*)(ws + WS_DEG);
    int*   off    = (int*)(ws + WS_OFF);
    int*   csr    = (int*)(ws + WS_CSR);
    unsigned short* Wt = (unsigned short*)(ws + WS_WT);

    hipMemsetAsync(d_ws, 0, WS_ZERO, stream);

    k_detect<<<1, 64, 0, stream>>>(ei, flag);
    k_prep<<<2048 + 128, 256, 0, stream>>>(x, xb, xq, Wl, Wr, Wt);
    k_bcount<<<512, 256, 0, stream>>>(ei, flag, cnt);
    k_scan<<<1, 256, 0, stream>>>(cnt, coff, cur);
    k_bin<<<(NE + RND - 1) / RND, 256, 0, stream>>>(ei, flag, cur, bin);
    k_csr<<<NB, 256, 0, stream>>>(bin, coff, csr, deg, off);
    k_agg<<<(NN * 64 + 255) / 256, 256, 0, stream>>>((const uint2*)xq, csr, deg, off, aggb);
    k_gemm<<<(NN + 127) / 128, 256, 0, stream>>>((const unsigned short*)aggb,
                                                 (const unsigned short*)xb,
                                                 Wt, bl, out_raw, bn_sum, bn_sq);
    k_norm<<<4096, 256, 0, stream>>>(out_raw, bn_sum, bn_sq, gamma, beta, out_bn);
}

// Round 19
// 211.977 us; speedup vs baseline: 1.3135x; 1.0648x over previous
//
#include <hip/hip_runtime.h>

constexpr int NN = 100000;
constexpr int NE = 3200000;
constexpr int DD = 128;
constexpr int NB = 782;          // ceil(NN/128) buckets of 128 nodes
constexpr int RND = 8192;        // edges binned per block
constexpr int NBLK = 391;        // ceil(NE/RND)
#define BN_EPS 1e-5f

typedef __attribute__((ext_vector_type(8))) short bf16x8;
typedef __attribute__((ext_vector_type(4))) float f32x4;
typedef __attribute__((ext_vector_type(2))) float f32x2;

// ---- workspace layout (bytes) ----
constexpr size_t WS_CNT   = 0;            // int[NB]
constexpr size_t WS_COFF  = 4096;         // int[NB+1]
constexpr size_t WS_FLAG  = 12288;        // int[1]
constexpr size_t WS_BNSUM = 12800;        // float[128]
constexpr size_t WS_BNSQ  = 13312;        // float[128]
constexpr size_t WS_ZERO  = 16384;        // memset range
constexpr size_t WS_DEG   = 16384;        // int[NN]
constexpr size_t WS_OFF   = 416384;       // int[NN]
constexpr size_t WS_CSR   = 816384;       // int[NE]
constexpr size_t WS_WT    = 13616384;     // ushort[128*256] transposed bf16 W (64KB)
// d_out first half (out_raw, 51.2MB):
//   xq   (fp8[NN*128], 12.8MB) at byte 0          dead after k_agg
//   cntM (int[NBLK*NB], 1.22MB) at byte 16M       dead after k_binB
//   gbR  (int[NBLK*NB], 1.22MB) at byte 20M       dead after k_binB
//   k_gemm overwrites the whole half with x_raw.
// d_out second half (out_bn): bin (uint[NE]) at [0,12.8M) until k_csr;
//   aggb (bf16[NN*128]) at [0,25.6M) from k_agg; xb (bf16[NN*128]) at [25.6M,51.2M).
//   All dead before k_norm writes x_deskewed.

__device__ inline unsigned bf16rne(float f) {
    unsigned u = __float_as_uint(f);
    return (u + 0x7fffu + ((u >> 16) & 1u)) >> 16;
}

#if __has_builtin(__builtin_amdgcn_cvt_pk_f32_fp8)
__device__ inline f32x2 fp8pk_lo(unsigned u) {
    return __builtin_amdgcn_cvt_pk_f32_fp8((int)u, false);
}
__device__ inline f32x2 fp8pk_hi(unsigned u) {
    return __builtin_amdgcn_cvt_pk_f32_fp8((int)u, true);
}
__device__ inline unsigned f32x4_to_fp8(float4 v) {
    int w = __builtin_amdgcn_cvt_pk_fp8_f32(v.x, v.y, 0, false);
    w = __builtin_amdgcn_cvt_pk_fp8_f32(v.z, v.w, w, true);
    return (unsigned)w;
}
#else
__device__ inline float fp8_to_f32_1(unsigned b) {
    unsigned s = (b & 0x80u) << 24;
    unsigned em = b & 0x7fu;
    float f;
    if (em >= 8) f = __uint_as_float((em << 20) + (120u << 23));
    else f = (float)em * 0.001953125f;
    return __uint_as_float(__float_as_uint(f) | s);
}
__device__ inline f32x2 fp8pk_lo(unsigned u) {
    f32x2 r;
    r[0] = fp8_to_f32_1(u & 0xffu);
    r[1] = fp8_to_f32_1((u >> 8) & 0xffu);
    return r;
}
__device__ inline f32x2 fp8pk_hi(unsigned u) {
    f32x2 r;
    r[0] = fp8_to_f32_1((u >> 16) & 0xffu);
    r[1] = fp8_to_f32_1((u >> 24) & 0xffu);
    return r;
}
__device__ inline unsigned f32_to_fp8_1(float f) {
    unsigned s = (__float_as_uint(f) >> 24) & 0x80u;
    float a = fabsf(f);
    if (!(a > 0.f)) return s;
    if (a >= 448.f) return s | 0x7Eu;
    int e = (int)(__float_as_uint(a) >> 23) - 127;
    if (e < -6) e = -6;
    float step = __uint_as_float((unsigned)(e - 3 + 127) << 23);
    int m = (int)rintf(a / step);
    if (m >= 16) { e += 1; m = 8; }
    if (m >= 8) return s | (unsigned)((e + 7) << 3) | (unsigned)(m - 8);
    return s | (unsigned)m;
}
__device__ inline unsigned f32x4_to_fp8(float4 v) {
    return f32_to_fp8_1(v.x) | (f32_to_fp8_1(v.y) << 8) |
           (f32_to_fp8_1(v.z) << 16) | (f32_to_fp8_1(v.w) << 24);
}
#endif

// accumulate 8 fp8 features from a uint2 into 4 packed f32x2 accumulators
#define ACC8(u)                                                              \
    {                                                                        \
        aa0 += fp8pk_lo((u).x);                                              \
        aa1 += fp8pk_hi((u).x);                                              \
        aa2 += fp8pk_lo((u).y);                                              \
        aa3 += fp8pk_hi((u).y);                                              \
    }

// Detect whether edge_index arrived as int64 (odd int32 words all zero).
__global__ void k_detect(const int* __restrict__ ei, int* __restrict__ flag) {
    int lane = threadIdx.x;
    int v = ei[2 * lane + 1];
    unsigned long long b = __ballot(v == 0);
    if (lane == 0) *flag = (b == ~0ull) ? 1 : 0;
}

// Build bf16 copy (GEMM), fp8 copy (gather), and transposed bf16 W, one kernel.
__global__ __launch_bounds__(256) void k_prep(const float* __restrict__ x,
                                              unsigned* __restrict__ xb,
                                              unsigned* __restrict__ xq,
                                              const float* __restrict__ Wl,
                                              const float* __restrict__ Wr,
                                              unsigned short* __restrict__ Wt) {
    int bid = blockIdx.x;
    if (bid < 2048) {
        int total = NN * DD / 4;
        for (int i = bid * 256 + threadIdx.x; i < total; i += 2048 * 256) {
            float4 v = ((const float4*)x)[i];
            unsigned a = (bf16rne(v.y) << 16) | bf16rne(v.x);
            unsigned b = (bf16rne(v.w) << 16) | bf16rne(v.z);
            ((uint2*)xb)[i] = make_uint2(a, b);
            xq[i] = f32x4_to_fp8(v);
        }
    } else {
        int idx = (bid - 2048) * 256 + threadIdx.x;   // 32768 total
        int n = idx >> 8, k = idx & 255;
        float v = (k < 128) ? Wl[(size_t)k * DD + n] : Wr[(size_t)(k - 128) * DD + n];
        Wt[idx] = (unsigned short)bf16rne(v);
    }
}

// Pass A: one vectorized dst pass -> per-block bucket histogram -> cntM row.
__global__ __launch_bounds__(256) void k_binA(const int* __restrict__ ei,
                                              const int* __restrict__ flag,
                                              int* __restrict__ cntM) {
    __shared__ int hist[NB];
    int tid = threadIdx.x;
    for (int i = tid; i < NB; i += 256) hist[i] = 0;
    __syncthreads();
    int i64 = *flag;
    int e0 = blockIdx.x * RND;
    int cntE = NE - e0; if (cntE > RND) cntE = RND;
    if (i64) {
        const int4* dp = (const int4*)(ei + 2 * (size_t)NE + 2 * (size_t)e0);
        int total = cntE >> 1;   // 2 edges per int4 (dst,0,dst,0)
        for (int k = tid; k < total; k += 256) {
            int4 v = dp[k];
            atomicAdd(&hist[v.x >> 7], 1);
            atomicAdd(&hist[v.z >> 7], 1);
        }
    } else {
        const int4* dp = (const int4*)(ei + (size_t)NE + e0);
        int total = cntE >> 2;   // 4 edges per int4
        for (int k = tid; k < total; k += 256) {
            int4 v = dp[k];
            atomicAdd(&hist[v.x >> 7], 1);
            atomicAdd(&hist[v.y >> 7], 1);
            atomicAdd(&hist[v.z >> 7], 1);
            atomicAdd(&hist[v.w >> 7], 1);
        }
    }
    __syncthreads();
    size_t base = (size_t)blockIdx.x * NB;
    for (int i = tid; i < NB; i += 256) cntM[base + i] = hist[i];
}

// Per-bucket column scan of cntM over the 391 blocks -> relative bases gbR,
// plus per-bucket totals cnt (for the global bucket-offset scan).
__global__ __launch_bounds__(512) void k_colscan(const int* __restrict__ cntM,
                                                 int* __restrict__ gbR,
                                                 int* __restrict__ cnt) {
    __shared__ int s[512];
    int b = blockIdx.x;
    int tid = threadIdx.x;
    int v = (tid < NBLK) ? cntM[(size_t)tid * NB + b] : 0;
    s[tid] = v;
    __syncthreads();
    for (int d = 1; d < 512; d <<= 1) {
        int t = (tid >= d) ? s[tid - d] : 0;
        __syncthreads();
        s[tid] += t;
        __syncthreads();
    }
    if (tid < NBLK) gbR[(size_t)tid * NB + b] = s[tid] - v;   // exclusive
    if (tid == NBLK - 1) cnt[b] = s[tid];                     // inclusive total
}

// Exclusive scan of the 782 bucket totals -> coff.
__global__ __launch_bounds__(256) void k_scan(const int* __restrict__ cnt,
                                              int* __restrict__ coff) {
    __shared__ int s[NB];
    for (int i = threadIdx.x; i < NB; i += 256) s[i] = cnt[i];
    __syncthreads();
    if (threadIdx.x == 0) {
        int acc = 0;
        for (int i = 0; i < NB; ++i) { int c = s[i]; s[i] = acc; acc += c; }
    }
    __syncthreads();
    for (int i = threadIdx.x; i < NB; i += 256) coff[i] = s[i];
    if (threadIdx.x == 0) coff[NB] = NE;
}

// Pass B: hist/bases come from cntM/gbR/coff (coalesced loads, no edge
// re-read for the histogram, no global atomics). LDS bucket-sort of edge
// indices, then COALESCED flush.
__global__ __launch_bounds__(256) void k_binB(const int* __restrict__ ei,
                                              const int* __restrict__ flag,
                                              const int* __restrict__ cntM,
                                              const int* __restrict__ gbR,
                                              const int* __restrict__ coff,
                                              unsigned* __restrict__ bin) {
    __shared__ int hist[NB];
    __shared__ int sbs[NB];
    __shared__ int gbase[NB];
    __shared__ int rk[NB];
    __shared__ int wsum[256];
    __shared__ unsigned short sj[RND];
    int tid = threadIdx.x;
    size_t mrow = (size_t)blockIdx.x * NB;
    for (int i = tid; i < NB; i += 256) {
        hist[i] = cntM[mrow + i];
        gbase[i] = coff[i] + gbR[mrow + i];
        rk[i] = 0;
    }
    __syncthreads();
    int i64 = *flag;
    int e0 = blockIdx.x * RND;
    int cntE = NE - e0; if (cntE > RND) cntE = RND;

    // exclusive scan hist -> sbs (4 buckets/thread + Hillis-Steele)
    int b4 = tid * 4;
    int l0 = (b4 + 0 < NB) ? hist[b4 + 0] : 0;
    int l1 = (b4 + 1 < NB) ? hist[b4 + 1] : 0;
    int l2 = (b4 + 2 < NB) ? hist[b4 + 2] : 0;
    int l3 = (b4 + 3 < NB) ? hist[b4 + 3] : 0;
    int tsum = l0 + l1 + l2 + l3;
    wsum[tid] = tsum;
    __syncthreads();
    for (int d = 1; d < 256; d <<= 1) {
        int v = (tid >= d) ? wsum[tid - d] : 0;
        __syncthreads();
        wsum[tid] += v;
        __syncthreads();
    }
    int p = wsum[tid] - tsum;
    if (b4 + 0 < NB) sbs[b4 + 0] = p;
    if (b4 + 1 < NB) sbs[b4 + 1] = p + l0;
    if (b4 + 2 < NB) sbs[b4 + 2] = p + l0 + l1;
    if (b4 + 3 < NB) sbs[b4 + 3] = p + l0 + l1 + l2;
    __syncthreads();

    // rank edges into LDS bucket order
    for (int j = tid; j < cntE; j += 256) {
        int e = e0 + j;
        int dst = i64 ? ei[2 * (NE + e)] : ei[NE + e];
        int b = dst >> 7;
        int r = atomicAdd(&rk[b], 1);
        sj[sbs[b] + r] = (unsigned short)j;
    }
    __syncthreads();

    // coalesced flush (consecutive t in a run -> consecutive addrs)
    for (int t = tid; t < cntE; t += 256) {
        int j = sj[t];
        int e = e0 + j;
        int src = i64 ? ei[2 * e] : ei[e];
        int dst = i64 ? ei[2 * (NE + e)] : ei[NE + e];
        int b = dst >> 7;
        bin[gbase[b] + (t - sbs[b])] = ((unsigned)src << 7) | (unsigned)(dst & 127);
    }
}

// Per-bucket counting sort -> node-grouped CSR (PRE-SCALED src*16 for k_agg's
// uint2 addressing) + deg/off.
__global__ __launch_bounds__(256) void k_csr(const unsigned* __restrict__ bin,
                                             const int* __restrict__ coff,
                                             int* __restrict__ csr,
                                             int* __restrict__ deg,
                                             int* __restrict__ off) {
    __shared__ int hist[128];
    __shared__ int sb[128];
    __shared__ int curs[128];
    int b = blockIdx.x;
    int tid = threadIdx.x;
    if (tid < 128) hist[tid] = 0;
    __syncthreads();
    int e0 = coff[b], e1 = coff[b + 1];
    for (int j = e0 + tid; j < e1; j += 256)
        atomicAdd(&hist[bin[j] & 127], 1);
    __syncthreads();
    if (tid == 0) {
        int acc = 0;
        for (int i = 0; i < 128; ++i) { sb[i] = acc; acc += hist[i]; }
    }
    __syncthreads();
    if (tid < 128) curs[tid] = sb[tid];
    __syncthreads();
    for (int j = e0 + tid; j < e1; j += 256) {
        unsigned p = bin[j];
        int d = p & 127;
        int r = atomicAdd(&curs[d], 1);
        csr[e0 + r] = (int)((p >> 7) << 4);   // src * 16 (uint2-row base)
    }
    int n = b * 128 + tid;
    if (tid < 128 && n < NN) {
        deg[n] = hist[tid];
        off[n] = e0 + sb[tid];
    }
}

// Wave-per-node gather-sum from the fp8 copy, 4 rows per wave-load,
// packed f32x2 accumulate. csr is pre-scaled (src*16): address = csrval + cl.
__global__ __launch_bounds__(256) void k_agg(const uint2* __restrict__ xq2,
                                             const int* __restrict__ csr,
                                             const int* __restrict__ deg,
                                             const int* __restrict__ off,
                                             unsigned* __restrict__ aggb) {
    int w = (blockIdx.x * 256 + threadIdx.x) >> 6;
    int lane = threadIdx.x & 63;
    if (w >= NN) return;
    int dg = deg[w];
    int o = off[w];
    int q = lane >> 4;       // edge sub-slot (0..3)
    int cl = lane & 15;      // uint2 slot within the 128B row
    const uint2* xp = xq2 + cl;
    f32x2 aa0 = {0.f, 0.f}, aa1 = {0.f, 0.f}, aa2 = {0.f, 0.f}, aa3 = {0.f, 0.f};

    int j = 0;
    for (; j + 16 <= dg; j += 16) {
        int s0 = csr[o + j + q];
        int s1 = csr[o + j + 4 + q];
        int s2 = csr[o + j + 8 + q];
        int s3 = csr[o + j + 12 + q];
        uint2 u0 = xp[s0];
        uint2 u1 = xp[s1];
        uint2 u2 = xp[s2];
        uint2 u3 = xp[s3];
        ACC8(u0); ACC8(u1); ACC8(u2); ACC8(u3);
    }
    for (; j + 4 <= dg; j += 4) {
        int s = csr[o + j + q];
        uint2 u = xp[s];
        ACC8(u);
    }
    int rem = dg - j;        // 0..3
    if (q < rem) {
        int s = csr[o + j + q];
        uint2 u = xp[s];
        ACC8(u);
    }

    float a0 = aa0[0], a1 = aa0[1], a2 = aa1[0], a3 = aa1[1];
    float a4 = aa2[0], a5 = aa2[1], a6 = aa3[0], a7 = aa3[1];
    a0 += __shfl_xor(a0, 16); a0 += __shfl_xor(a0, 32);
    a1 += __shfl_xor(a1, 16); a1 += __shfl_xor(a1, 32);
    a2 += __shfl_xor(a2, 16); a2 += __shfl_xor(a2, 32);
    a3 += __shfl_xor(a3, 16); a3 += __shfl_xor(a3, 32);
    a4 += __shfl_xor(a4, 16); a4 += __shfl_xor(a4, 32);
    a5 += __shfl_xor(a5, 16); a5 += __shfl_xor(a5, 32);
    a6 += __shfl_xor(a6, 16); a6 += __shfl_xor(a6, 32);
    a7 += __shfl_xor(a7, 16); a7 += __shfl_xor(a7, 32);

    if (lane < 16) {
        float inv = 1.0f / fmaxf((float)dg, 1.0f);
        uint4 p;
        p.x = (bf16rne(a1 * inv) << 16) | bf16rne(a0 * inv);
        p.y = (bf16rne(a3 * inv) << 16) | bf16rne(a2 * inv);
        p.z = (bf16rne(a5 * inv) << 16) | bf16rne(a4 * inv);
        p.w = (bf16rne(a7 * inv) << 16) | bf16rne(a6 * inv);
        ((uint4*)aggb)[(size_t)w * 16 + cl] = p;
    }
}

// MFMA GEMM: x_raw = [agg | x]_bf16 @ Wt^T + b, BN stats fused into epilogue.
// Wt staged in LDS (528B padded stride); all 16 A-fragments preloaded.
__global__ __launch_bounds__(256) void k_gemm(const unsigned short* __restrict__ aggb,
                                              const unsigned short* __restrict__ xb,
                                              const unsigned short* __restrict__ Wt,
                                              const float* __restrict__ bl,
                                              float* __restrict__ out_raw,
                                              float* __restrict__ bn_sum,
                                              float* __restrict__ bn_sq) {
    __shared__ unsigned short sW[128][264];   // 67.6 KB, stride 528B
    __shared__ float s_s[4][128];
    __shared__ float s_q[4][128];
    int tid = threadIdx.x;
    int wv = tid >> 6, lane = tid & 63;
    int l15 = lane & 15, lhi = lane >> 4;
    int mr = blockIdx.x * 128 + wv * 32;

    // stage Wt (64KB) into LDS
    {
        const uint4* g = (const uint4*)Wt;
        #pragma unroll
        for (int it = 0; it < 16; ++it) {
            int c = tid + it * 256;
            int row = c >> 5;
            int col = (c & 31) * 8;
            *(uint4*)&sW[row][col] = g[c];
        }
    }

    int r0 = mr + l15;       if (r0 > NN - 1) r0 = NN - 1;
    int r1 = mr + 16 + l15;  if (r1 > NN - 1) r1 = NN - 1;
    const unsigned short* a0p = aggb + (size_t)r0 * DD;
    const unsigned short* a1p = aggb + (size_t)r1 * DD;
    const unsigned short* x0p = xb + (size_t)r0 * DD;
    const unsigned short* x1p = xb + (size_t)r1 * DD;

    // preload all 16 A fragments
    bf16x8 A0[8], A1[8];
    #pragma unroll
    for (int ks = 0; ks < 8; ++ks) {
        int kk = (ks & 3) * 32 + lhi * 8;
        if (ks < 4) {
            A0[ks] = *(const bf16x8*)(a0p + kk);
            A1[ks] = *(const bf16x8*)(a1p + kk);
        } else {
            A0[ks] = *(const bf16x8*)(x0p + kk);
            A1[ks] = *(const bf16x8*)(x1p + kk);
        }
    }

    f32x4 acc[2][8];
    #pragma unroll
    for (int m = 0; m < 2; ++m)
        #pragma unroll
        for (int nt = 0; nt < 8; ++nt)
            acc[m][nt] = (f32x4){0.f, 0.f, 0.f, 0.f};

    __syncthreads();

    #pragma unroll
    for (int ks = 0; ks < 8; ++ks) {
        #pragma unroll
        for (int nt = 0; nt < 8; ++nt) {
            bf16x8 b = *(const bf16x8*)&sW[nt * 16 + l15][ks * 32 + lhi * 8];
            acc[0][nt] = __builtin_amdgcn_mfma_f32_16x16x32_bf16(A0[ks], b, acc[0][nt], 0, 0, 0);
            acc[1][nt] = __builtin_amdgcn_mfma_f32_16x16x32_bf16(A1[ks], b, acc[1][nt], 0, 0, 0);
        }
    }

    // epilogue: bias + store (D layout: row=lhi*4+reg, col=l15) + column stats
    float bias8[8];
    #pragma unroll
    for (int nt = 0; nt < 8; ++nt) bias8[nt] = bl[nt * 16 + l15];

    float s8[8] = {}, q8[8] = {};
    #pragma unroll
    for (int m = 0; m < 2; ++m) {
        #pragma unroll
        for (int r = 0; r < 4; ++r) {
            int row = mr + m * 16 + lhi * 4 + r;
            if (row < NN) {
                #pragma unroll
                for (int nt = 0; nt < 8; ++nt) {
                    float v = acc[m][nt][r] + bias8[nt];
                    out_raw[(size_t)row * DD + nt * 16 + l15] = v;
                    s8[nt] += v;
                    q8[nt] += v * v;
                }
            }
        }
    }

    #pragma unroll
    for (int nt = 0; nt < 8; ++nt) {
        s8[nt] += __shfl_xor(s8[nt], 16);
        s8[nt] += __shfl_xor(s8[nt], 32);
        q8[nt] += __shfl_xor(q8[nt], 16);
        q8[nt] += __shfl_xor(q8[nt], 32);
    }
    if (lhi == 0) {
        #pragma unroll
        for (int nt = 0; nt < 8; ++nt) {
            s_s[wv][nt * 16 + l15] = s8[nt];
            s_q[wv][nt * 16 + l15] = q8[nt];
        }
    }
    __syncthreads();
    if (tid < 128) {
        float ts = s_s[0][tid] + s_s[1][tid] + s_s[2][tid] + s_s[3][tid];
        float tq = s_q[0][tid] + s_q[1][tid] + s_q[2][tid] + s_q[3][tid];
        atomicAdd(&bn_sum[tid], ts);
        atomicAdd(&bn_sq[tid], tq);
    }
}

__global__ __launch_bounds__(256) void k_norm(const float* __restrict__ raw,
                                              const float* __restrict__ bn_sum,
                                              const float* __restrict__ bn_sq,
                                              const float* __restrict__ gamma,
                                              const float* __restrict__ beta,
                                              float* __restrict__ out) {
    const float invN = 1.0f / (float)NN;
    int total = NN * DD / 4;
    for (int idx = blockIdx.x * 256 + threadIdx.x; idx < total; idx += gridDim.x * 256) {
        int cp = idx & 31;
        float4 v = ((const float4*)raw)[idx];
        float4 s = ((const float4*)bn_sum)[cp];
        float4 q = ((const float4*)bn_sq)[cp];
        float4 g = ((const float4*)gamma)[cp];
        float4 b = ((const float4*)beta)[cp];
        float4 o;
        { float mu = s.x * invN; float var = q.x * invN - mu * mu;
          o.x = (v.x - mu) * rsqrtf(var + BN_EPS) * g.x + b.x; }
        { float mu = s.y * invN; float var = q.y * invN - mu * mu;
          o.y = (v.y - mu) * rsqrtf(var + BN_EPS) * g.y + b.y; }
        { float mu = s.z * invN; float var = q.z * invN - mu * mu;
          o.z = (v.z - mu) * rsqrtf(var + BN_EPS) * g.z + b.z; }
        { float mu = s.w * invN; float var = q.w * invN - mu * mu;
          o.w = (v.w - mu) * rsqrtf(var + BN_EPS) * g.w + b.w; }
        ((float4*)out)[idx] = o;
    }
}

extern "C" void kernel_launch(void* const* d_in, const int* in_sizes, int n_in,
                              void* d_out, int out_size, void* d_ws, size_t ws_size,
                              hipStream_t stream) {
    const float* x     = (const float*)d_in[0];
    const int*   ei    = (const int*)d_in[1];
    const float* Wl    = (const float*)d_in[2];
    const float* bl    = (const float*)d_in[3];
    const float* Wr    = (const float*)d_in[4];
    const float* gamma = (const float*)d_in[5];
    const float* beta  = (const float*)d_in[6];

    float* out_raw = (float*)d_out;                       // [NN][DD] x_raw
    float* out_bn  = out_raw + (size_t)NN * DD;           // [NN][DD] x_deskewed
    unsigned* xq   = (unsigned*)d_out;                    // fp8[NN*128] in out_raw half
    int*      cntM = (int*)((char*)d_out + 16000000);     // int[NBLK*NB], dead before gemm
    int*      gbR  = (int*)((char*)d_out + 20000000);     // int[NBLK*NB], dead before gemm
    unsigned* bin  = (unsigned*)out_bn;                   // uint[NE]
    unsigned* aggb = (unsigned*)out_bn;                   // bf16[NN*128] packed
    unsigned* xb   = (unsigned*)((char*)out_bn + (size_t)NN * DD * 2); // bf16[NN*128]

    char* ws = (char*)d_ws;
    int*   cnt    = (int*)(ws + WS_CNT);
    int*   coff   = (int*)(ws + WS_COFF);
    int*   flag   = (int*)(ws + WS_FLAG);
    float* bn_sum = (float*)(ws + WS_BNSUM);
    float* bn_sq  = (float*)(ws + WS_BNSQ);
    int*   deg    = (int*)(ws + WS_DEG);
    int*   off    = (int*)(ws + WS_OFF);
    int*   csr    = (int*)(ws + WS_CSR);
    unsigned short* Wt = (unsigned short*)(ws + WS_WT);

    hipMemsetAsync(d_ws, 0, WS_ZERO, stream);

    k_detect<<<1, 64, 0, stream>>>(ei, flag);
    k_prep<<<2048 + 128, 256, 0, stream>>>(x, xb, xq, Wl, Wr, Wt);
    k_binA<<<NBLK, 256, 0, stream>>>(ei, flag, cntM);
    k_colscan<<<NB, 512, 0, stream>>>(cntM, gbR, cnt);
    k_scan<<<1, 256, 0, stream>>>(cnt, coff);
    k_binB<<<NBLK, 256, 0, stream>>>(ei, flag, cntM, gbR, coff, bin);
    k_csr<<<NB, 256, 0, stream>>>(bin, coff, csr, deg, off);
    k_agg<<<(NN * 64 + 255) / 256, 256, 0, stream>>>((const uint2*)xq, csr, deg, off, aggb);
    k_gemm<<<(NN + 127) / 128, 256, 0, stream>>>((const unsigned short*)aggb,
                                                 (const unsigned short*)xb,
                                                 Wt, bl, out_raw, bn_sum, bn_sq);
    k_norm<<<4096, 256, 0, stream>>>(out_raw, bn_sum, bn_sq, gamma, beta, out_bn);
}

// Round 21
// 209.775 us; speedup vs baseline: 1.3273x; 1.0105x over previous
//
#include <hip/hip_runtime.h>

constexpr int NN = 100000;
constexpr int NE = 3200000;
constexpr int DD = 128;
constexpr int NB = 782;          // ceil(NN/128) buckets of 128 nodes
constexpr int RND = 8192;        // edges binned per block
constexpr int NBLK = 391;        // ceil(NE/RND)
#define BN_EPS 1e-5f

typedef __attribute__((ext_vector_type(8))) short bf16x8;
typedef __attribute__((ext_vector_type(4))) float f32x4;
typedef __attribute__((ext_vector_type(2))) float f32x2;

// ---- workspace layout (bytes) ----
constexpr size_t WS_CNT   = 0;            // int[NB]
constexpr size_t WS_COFF  = 4096;         // int[NB+1]
constexpr size_t WS_FLAG  = 12288;        // int[1]
constexpr size_t WS_BNSUM = 12800;        // float[128]
constexpr size_t WS_BNSQ  = 13312;        // float[128]
constexpr size_t WS_ZERO  = 16384;        // memset range
constexpr size_t WS_DEG   = 16384;        // int[NN]
constexpr size_t WS_OFF   = 416384;       // int[NN]
constexpr size_t WS_CSR   = 816384;       // int[NE]
constexpr size_t WS_WT    = 13616384;     // ushort[128*256] transposed bf16 W (64KB)
// d_out first half (out_raw, 51.2MB):
//   xq   (fp8[NN*128], 12.8MB) at byte 0          dead after k_agg
//   cntM (int[NBLK*NB], 1.22MB) at byte 16M       dead after k_binB
//   gbR  (int[NBLK*NB], 1.22MB) at byte 20M       dead after k_binB
//   k_gemm overwrites the whole half with x_raw.
// d_out second half (out_bn): bin (uint[NE]) at [0,12.8M) until k_csr;
//   aggb (bf16[NN*128]) at [0,25.6M) from k_agg; xb (bf16[NN*128]) at [25.6M,51.2M).
//   All dead before k_norm writes x_deskewed.

__device__ inline unsigned bf16rne(float f) {
    unsigned u = __float_as_uint(f);
    return (u + 0x7fffu + ((u >> 16) & 1u)) >> 16;
}

#if __has_builtin(__builtin_amdgcn_cvt_pk_f32_fp8)
__device__ inline f32x2 fp8pk_lo(unsigned u) {
    return __builtin_amdgcn_cvt_pk_f32_fp8((int)u, false);
}
__device__ inline f32x2 fp8pk_hi(unsigned u) {
    return __builtin_amdgcn_cvt_pk_f32_fp8((int)u, true);
}
__device__ inline unsigned f32x4_to_fp8(float4 v) {
    int w = __builtin_amdgcn_cvt_pk_fp8_f32(v.x, v.y, 0, false);
    w = __builtin_amdgcn_cvt_pk_fp8_f32(v.z, v.w, w, true);
    return (unsigned)w;
}
#else
__device__ inline float fp8_to_f32_1(unsigned b) {
    unsigned s = (b & 0x80u) << 24;
    unsigned em = b & 0x7fu;
    float f;
    if (em >= 8) f = __uint_as_float((em << 20) + (120u << 23));
    else f = (float)em * 0.001953125f;
    return __uint_as_float(__float_as_uint(f) | s);
}
__device__ inline f32x2 fp8pk_lo(unsigned u) {
    f32x2 r;
    r[0] = fp8_to_f32_1(u & 0xffu);
    r[1] = fp8_to_f32_1((u >> 8) & 0xffu);
    return r;
}
__device__ inline f32x2 fp8pk_hi(unsigned u) {
    f32x2 r;
    r[0] = fp8_to_f32_1((u >> 16) & 0xffu);
    r[1] = fp8_to_f32_1((u >> 24) & 0xffu);
    return r;
}
__device__ inline unsigned f32_to_fp8_1(float f) {
    unsigned s = (__float_as_uint(f) >> 24) & 0x80u;
    float a = fabsf(f);
    if (!(a > 0.f)) return s;
    if (a >= 448.f) return s | 0x7Eu;
    int e = (int)(__float_as_uint(a) >> 23) - 127;
    if (e < -6) e = -6;
    float step = __uint_as_float((unsigned)(e - 3 + 127) << 23);
    int m = (int)rintf(a / step);
    if (m >= 16) { e += 1; m = 8; }
    if (m >= 8) return s | (unsigned)((e + 7) << 3) | (unsigned)(m - 8);
    return s | (unsigned)m;
}
__device__ inline unsigned f32x4_to_fp8(float4 v) {
    return f32_to_fp8_1(v.x) | (f32_to_fp8_1(v.y) << 8) |
           (f32_to_fp8_1(v.z) << 16) | (f32_to_fp8_1(v.w) << 24);
}
#endif

// accumulate 8 fp8 features from a uint2 into 4 packed f32x2 accumulators
#define ACC8(u)                                                              \
    {                                                                        \
        aa0 += fp8pk_lo((u).x);                                              \
        aa1 += fp8pk_hi((u).x);                                              \
        aa2 += fp8pk_lo((u).y);                                              \
        aa3 += fp8pk_hi((u).y);                                              \
    }

// Detect whether edge_index arrived as int64 (odd int32 words all zero).
__global__ void k_detect(const int* __restrict__ ei, int* __restrict__ flag) {
    int lane = threadIdx.x;
    int v = ei[2 * lane + 1];
    unsigned long long b = __ballot(v == 0);
    if (lane == 0) *flag = (b == ~0ull) ? 1 : 0;
}

// Build bf16 copy (GEMM), fp8 copy (gather), and transposed bf16 W, one kernel.
__global__ __launch_bounds__(256) void k_prep(const float* __restrict__ x,
                                              unsigned* __restrict__ xb,
                                              unsigned* __restrict__ xq,
                                              const float* __restrict__ Wl,
                                              const float* __restrict__ Wr,
                                              unsigned short* __restrict__ Wt) {
    int bid = blockIdx.x;
    if (bid < 2048) {
        int total = NN * DD / 4;
        for (int i = bid * 256 + threadIdx.x; i < total; i += 2048 * 256) {
            float4 v = ((const float4*)x)[i];
            unsigned a = (bf16rne(v.y) << 16) | bf16rne(v.x);
            unsigned b = (bf16rne(v.w) << 16) | bf16rne(v.z);
            ((uint2*)xb)[i] = make_uint2(a, b);
            xq[i] = f32x4_to_fp8(v);
        }
    } else {
        int idx = (bid - 2048) * 256 + threadIdx.x;   // 32768 total
        int n = idx >> 8, k = idx & 255;
        float v = (k < 128) ? Wl[(size_t)k * DD + n] : Wr[(size_t)(k - 128) * DD + n];
        Wt[idx] = (unsigned short)bf16rne(v);
    }
}

// Pass A: one vectorized dst pass -> per-block bucket histogram -> cntM row.
__global__ __launch_bounds__(256) void k_binA(const int* __restrict__ ei,
                                              const int* __restrict__ flag,
                                              int* __restrict__ cntM) {
    __shared__ int hist[NB];
    int tid = threadIdx.x;
    for (int i = tid; i < NB; i += 256) hist[i] = 0;
    __syncthreads();
    int i64 = *flag;
    int e0 = blockIdx.x * RND;
    int cntE = NE - e0; if (cntE > RND) cntE = RND;
    if (i64) {
        const int4* dp = (const int4*)(ei + 2 * (size_t)NE + 2 * (size_t)e0);
        int total = cntE >> 1;
        for (int k = tid; k < total; k += 256) {
            int4 v = dp[k];
            atomicAdd(&hist[v.x >> 7], 1);
            atomicAdd(&hist[v.z >> 7], 1);
        }
    } else {
        const int4* dp = (const int4*)(ei + (size_t)NE + e0);
        int total = cntE >> 2;
        for (int k = tid; k < total; k += 256) {
            int4 v = dp[k];
            atomicAdd(&hist[v.x >> 7], 1);
            atomicAdd(&hist[v.y >> 7], 1);
            atomicAdd(&hist[v.z >> 7], 1);
            atomicAdd(&hist[v.w >> 7], 1);
        }
    }
    __syncthreads();
    size_t base = (size_t)blockIdx.x * NB;
    for (int i = tid; i < NB; i += 256) cntM[base + i] = hist[i];
}

// Per-bucket column scan of cntM over the 391 blocks -> relative bases gbR,
// plus per-bucket totals cnt.
__global__ __launch_bounds__(512) void k_colscan(const int* __restrict__ cntM,
                                                 int* __restrict__ gbR,
                                                 int* __restrict__ cnt) {
    __shared__ int s[512];
    int b = blockIdx.x;
    int tid = threadIdx.x;
    int v = (tid < NBLK) ? cntM[(size_t)tid * NB + b] : 0;
    s[tid] = v;
    __syncthreads();
    for (int d = 1; d < 512; d <<= 1) {
        int t = (tid >= d) ? s[tid - d] : 0;
        __syncthreads();
        s[tid] += t;
        __syncthreads();
    }
    if (tid < NBLK) gbR[(size_t)tid * NB + b] = s[tid] - v;
    if (tid == NBLK - 1) cnt[b] = s[tid];
}

// Exclusive scan of the 782 bucket totals -> coff.
__global__ __launch_bounds__(256) void k_scan(const int* __restrict__ cnt,
                                              int* __restrict__ coff) {
    __shared__ int s[NB];
    for (int i = threadIdx.x; i < NB; i += 256) s[i] = cnt[i];
    __syncthreads();
    if (threadIdx.x == 0) {
        int acc = 0;
        for (int i = 0; i < NB; ++i) { int c = s[i]; s[i] = acc; acc += c; }
    }
    __syncthreads();
    for (int i = threadIdx.x; i < NB; i += 256) coff[i] = s[i];
    if (threadIdx.x == 0) coff[NB] = NE;
}

// Pass B: hist/bases from cntM/gbR/coff (coalesced loads, no global atomics).
// LDS bucket-sort of edge indices, then COALESCED flush. (dst re-read in the
// flush pass — L2-hot; the u16 bucket-cache variant was wrong: dst needs 17b.)
__global__ __launch_bounds__(256) void k_binB(const int* __restrict__ ei,
                                              const int* __restrict__ flag,
                                              const int* __restrict__ cntM,
                                              const int* __restrict__ gbR,
                                              const int* __restrict__ coff,
                                              unsigned* __restrict__ bin) {
    __shared__ int hist[NB];
    __shared__ int sbs[NB];
    __shared__ int gbase[NB];
    __shared__ int rk[NB];
    __shared__ int wsum[256];
    __shared__ unsigned short sj[RND];
    int tid = threadIdx.x;
    size_t mrow = (size_t)blockIdx.x * NB;
    for (int i = tid; i < NB; i += 256) {
        hist[i] = cntM[mrow + i];
        gbase[i] = coff[i] + gbR[mrow + i];
        rk[i] = 0;
    }
    __syncthreads();
    int i64 = *flag;
    int e0 = blockIdx.x * RND;
    int cntE = NE - e0; if (cntE > RND) cntE = RND;

    // exclusive scan hist -> sbs (4 buckets/thread + Hillis-Steele)
    int b4 = tid * 4;
    int l0 = (b4 + 0 < NB) ? hist[b4 + 0] : 0;
    int l1 = (b4 + 1 < NB) ? hist[b4 + 1] : 0;
    int l2 = (b4 + 2 < NB) ? hist[b4 + 2] : 0;
    int l3 = (b4 + 3 < NB) ? hist[b4 + 3] : 0;
    int tsum = l0 + l1 + l2 + l3;
    wsum[tid] = tsum;
    __syncthreads();
    for (int d = 1; d < 256; d <<= 1) {
        int v = (tid >= d) ? wsum[tid - d] : 0;
        __syncthreads();
        wsum[tid] += v;
        __syncthreads();
    }
    int p = wsum[tid] - tsum;
    if (b4 + 0 < NB) sbs[b4 + 0] = p;
    if (b4 + 1 < NB) sbs[b4 + 1] = p + l0;
    if (b4 + 2 < NB) sbs[b4 + 2] = p + l0 + l1;
    if (b4 + 3 < NB) sbs[b4 + 3] = p + l0 + l1 + l2;
    __syncthreads();

    // rank edges into LDS bucket order
    for (int j = tid; j < cntE; j += 256) {
        int e = e0 + j;
        int dst = i64 ? ei[2 * (NE + e)] : ei[NE + e];
        int b = dst >> 7;
        int r = atomicAdd(&rk[b], 1);
        sj[sbs[b] + r] = (unsigned short)j;
    }
    __syncthreads();

    // coalesced flush (consecutive t in a run -> consecutive addrs)
    for (int t = tid; t < cntE; t += 256) {
        int j = sj[t];
        int e = e0 + j;
        int src = i64 ? ei[2 * e] : ei[e];
        int dst = i64 ? ei[2 * (NE + e)] : ei[NE + e];
        int b = dst >> 7;
        bin[gbase[b] + (t - sbs[b])] = ((unsigned)src << 7) | (unsigned)(dst & 127);
    }
}

// Per-bucket counting sort -> node-grouped CSR (pre-scaled src*16) + deg/off.
// Both bin passes vectorized as uint2 with scalar head/tail.
__global__ __launch_bounds__(256) void k_csr(const unsigned* __restrict__ bin,
                                             const int* __restrict__ coff,
                                             int* __restrict__ csr,
                                             int* __restrict__ deg,
                                             int* __restrict__ off) {
    __shared__ int hist[128];
    __shared__ int sb[128];
    __shared__ int curs[128];
    int b = blockIdx.x;
    int tid = threadIdx.x;
    if (tid < 128) hist[tid] = 0;
    __syncthreads();
    int e0 = coff[b], e1 = coff[b + 1];
    int a0 = (e0 + 1) & ~1;               // first even index >= e0
    int a1 = e1 & ~1;                     // last even index <= e1
    if (tid == 0 && e0 < a0) atomicAdd(&hist[bin[e0] & 127], 1);
    {
        const uint2* bp = (const uint2*)(bin + a0);
        int total = (a1 - a0) >> 1;
        for (int k = tid; k < total; k += 256) {
            uint2 v = bp[k];
            atomicAdd(&hist[v.x & 127], 1);
            atomicAdd(&hist[v.y & 127], 1);
        }
    }
    if (tid == 0 && a1 < e1) atomicAdd(&hist[bin[a1] & 127], 1);
    __syncthreads();
    if (tid == 0) {
        int acc = 0;
        for (int i = 0; i < 128; ++i) { sb[i] = acc; acc += hist[i]; }
    }
    __syncthreads();
    if (tid < 128) curs[tid] = sb[tid];
    __syncthreads();
    if (tid == 0 && e0 < a0) {
        unsigned p = bin[e0];
        int r = atomicAdd(&curs[p & 127], 1);
        csr[e0 + r] = (int)((p >> 7) << 4);
    }
    {
        const uint2* bp = (const uint2*)(bin + a0);
        int total = (a1 - a0) >> 1;
        for (int k = tid; k < total; k += 256) {
            uint2 v = bp[k];
            int r0 = atomicAdd(&curs[v.x & 127], 1);
            csr[e0 + r0] = (int)((v.x >> 7) << 4);
            int r1 = atomicAdd(&curs[v.y & 127], 1);
            csr[e0 + r1] = (int)((v.y >> 7) << 4);
        }
    }
    if (tid == 0 && a1 < e1) {
        unsigned p = bin[a1];
        int r = atomicAdd(&curs[p & 127], 1);
        csr[e0 + r] = (int)((p >> 7) << 4);
    }
    int n = b * 128 + tid;
    if (tid < 128 && n < NN) {
        deg[n] = hist[tid];
        off[n] = e0 + sb[tid];
    }
}

// Wave-per-node gather-sum from the fp8 copy, 4 rows per wave-load,
// packed f32x2 accumulate. csr is pre-scaled (src*16): address = csrval + cl.
__global__ __launch_bounds__(256) void k_agg(const uint2* __restrict__ xq2,
                                             const int* __restrict__ csr,
                                             const int* __restrict__ deg,
                                             const int* __restrict__ off,
                                             unsigned* __restrict__ aggb) {
    int w = (blockIdx.x * 256 + threadIdx.x) >> 6;
    int lane = threadIdx.x & 63;
    if (w >= NN) return;
    int dg = deg[w];
    int o = off[w];
    int q = lane >> 4;       // edge sub-slot (0..3)
    int cl = lane & 15;      // uint2 slot within the 128B row
    const uint2* xp = xq2 + cl;
    f32x2 aa0 = {0.f, 0.f}, aa1 = {0.f, 0.f}, aa2 = {0.f, 0.f}, aa3 = {0.f, 0.f};

    int j = 0;
    for (; j + 16 <= dg; j += 16) {
        int s0 = csr[o + j + q];
        int s1 = csr[o + j + 4 + q];
        int s2 = csr[o + j + 8 + q];
        int s3 = csr[o + j + 12 + q];
        uint2 u0 = xp[s0];
        uint2 u1 = xp[s1];
        uint2 u2 = xp[s2];
        uint2 u3 = xp[s3];
        ACC8(u0); ACC8(u1); ACC8(u2); ACC8(u3);
    }
    for (; j + 4 <= dg; j += 4) {
        int s = csr[o + j + q];
        uint2 u = xp[s];
        ACC8(u);
    }
    int rem = dg - j;        // 0..3
    if (q < rem) {
        int s = csr[o + j + q];
        uint2 u = xp[s];
        ACC8(u);
    }

    float a0 = aa0[0], a1 = aa0[1], a2 = aa1[0], a3 = aa1[1];
    float a4 = aa2[0], a5 = aa2[1], a6 = aa3[0], a7 = aa3[1];
    a0 += __shfl_xor(a0, 16); a0 += __shfl_xor(a0, 32);
    a1 += __shfl_xor(a1, 16); a1 += __shfl_xor(a1, 32);
    a2 += __shfl_xor(a2, 16); a2 += __shfl_xor(a2, 32);
    a3 += __shfl_xor(a3, 16); a3 += __shfl_xor(a3, 32);
    a4 += __shfl_xor(a4, 16); a4 += __shfl_xor(a4, 32);
    a5 += __shfl_xor(a5, 16); a5 += __shfl_xor(a5, 32);
    a6 += __shfl_xor(a6, 16); a6 += __shfl_xor(a6, 32);
    a7 += __shfl_xor(a7, 16); a7 += __shfl_xor(a7, 32);

    if (lane < 16) {
        float inv = 1.0f / fmaxf((float)dg, 1.0f);
        uint4 p;
        p.x = (bf16rne(a1 * inv) << 16) | bf16rne(a0 * inv);
        p.y = (bf16rne(a3 * inv) << 16) | bf16rne(a2 * inv);
        p.z = (bf16rne(a5 * inv) << 16) | bf16rne(a4 * inv);
        p.w = (bf16rne(a7 * inv) << 16) | bf16rne(a6 * inv);
        ((uint4*)aggb)[(size_t)w * 16 + cl] = p;
    }
}

// MFMA GEMM: x_raw = [agg | x]_bf16 @ Wt^T + b, BN stats fused into epilogue.
// Wt staged in LDS (528B padded stride); all 16 A-fragments preloaded.
__global__ __launch_bounds__(256) void k_gemm(const unsigned short* __restrict__ aggb,
                                              const unsigned short* __restrict__ xb,
                                              const unsigned short* __restrict__ Wt,
                                              const float* __restrict__ bl,
                                              float* __restrict__ out_raw,
                                              float* __restrict__ bn_sum,
                                              float* __restrict__ bn_sq) {
    __shared__ unsigned short sW[128][264];   // 67.6 KB, stride 528B
    __shared__ float s_s[4][128];
    __shared__ float s_q[4][128];
    int tid = threadIdx.x;
    int wv = tid >> 6, lane = tid & 63;
    int l15 = lane & 15, lhi = lane >> 4;
    int mr = blockIdx.x * 128 + wv * 32;

    // stage Wt (64KB) into LDS
    {
        const uint4* g = (const uint4*)Wt;
        #pragma unroll
        for (int it = 0; it < 16; ++it) {
            int c = tid + it * 256;
            int row = c >> 5;
            int col = (c & 31) * 8;
            *(uint4*)&sW[row][col] = g[c];
        }
    }

    int r0 = mr + l15;       if (r0 > NN - 1) r0 = NN - 1;
    int r1 = mr + 16 + l15;  if (r1 > NN - 1) r1 = NN - 1;
    const unsigned short* a0p = aggb + (size_t)r0 * DD;
    const unsigned short* a1p = aggb + (size_t)r1 * DD;
    const unsigned short* x0p = xb + (size_t)r0 * DD;
    const unsigned short* x1p = xb + (size_t)r1 * DD;

    // preload all 16 A fragments
    bf16x8 A0[8], A1[8];
    #pragma unroll
    for (int ks = 0; ks < 8; ++ks) {
        int kk = (ks & 3) * 32 + lhi * 8;
        if (ks < 4) {
            A0[ks] = *(const bf16x8*)(a0p + kk);
            A1[ks] = *(const bf16x8*)(a1p + kk);
        } else {
            A0[ks] = *(const bf16x8*)(x0p + kk);
            A1[ks] = *(const bf16x8*)(x1p + kk);
        }
    }

    f32x4 acc[2][8];
    #pragma unroll
    for (int m = 0; m < 2; ++m)
        #pragma unroll
        for (int nt = 0; nt < 8; ++nt)
            acc[m][nt] = (f32x4){0.f, 0.f, 0.f, 0.f};

    __syncthreads();

    #pragma unroll
    for (int ks = 0; ks < 8; ++ks) {
        #pragma unroll
        for (int nt = 0; nt < 8; ++nt) {
            bf16x8 b = *(const bf16x8*)&sW[nt * 16 + l15][ks * 32 + lhi * 8];
            acc[0][nt] = __builtin_amdgcn_mfma_f32_16x16x32_bf16(A0[ks], b, acc[0][nt], 0, 0, 0);
            acc[1][nt] = __builtin_amdgcn_mfma_f32_16x16x32_bf16(A1[ks], b, acc[1][nt], 0, 0, 0);
        }
    }

    // epilogue: bias + store (D layout: row=lhi*4+reg, col=l15) + column stats
    float bias8[8];
    #pragma unroll
    for (int nt = 0; nt < 8; ++nt) bias8[nt] = bl[nt * 16 + l15];

    float s8[8] = {}, q8[8] = {};
    #pragma unroll
    for (int m = 0; m < 2; ++m) {
        #pragma unroll
        for (int r = 0; r < 4; ++r) {
            int row = mr + m * 16 + lhi * 4 + r;
            if (row < NN) {
                #pragma unroll
                for (int nt = 0; nt < 8; ++nt) {
                    float v = acc[m][nt][r] + bias8[nt];
                    out_raw[(size_t)row * DD + nt * 16 + l15] = v;
                    s8[nt] += v;
                    q8[nt] += v * v;
                }
            }
        }
    }

    #pragma unroll
    for (int nt = 0; nt < 8; ++nt) {
        s8[nt] += __shfl_xor(s8[nt], 16);
        s8[nt] += __shfl_xor(s8[nt], 32);
        q8[nt] += __shfl_xor(q8[nt], 16);
        q8[nt] += __shfl_xor(q8[nt], 32);
    }
    if (lhi == 0) {
        #pragma unroll
        for (int nt = 0; nt < 8; ++nt) {
            s_s[wv][nt * 16 + l15] = s8[nt];
            s_q[wv][nt * 16 + l15] = q8[nt];
        }
    }
    __syncthreads();
    if (tid < 128) {
        float ts = s_s[0][tid] + s_s[1][tid] + s_s[2][tid] + s_s[3][tid];
        float tq = s_q[0][tid] + s_q[1][tid] + s_q[2][tid] + s_q[3][tid];
        atomicAdd(&bn_sum[tid], ts);
        atomicAdd(&bn_sq[tid], tq);
    }
}

__global__ __launch_bounds__(256) void k_norm(const float* __restrict__ raw,
                                              const float* __restrict__ bn_sum,
                                              const float* __restrict__ bn_sq,
                                              const float* __restrict__ gamma,
                                              const float* __restrict__ beta,
                                              float* __restrict__ out) {
    const float invN = 1.0f / (float)NN;
    int total = NN * DD / 4;
    for (int idx = blockIdx.x * 256 + threadIdx.x; idx < total; idx += gridDim.x * 256) {
        int cp = idx & 31;
        float4 v = ((const float4*)raw)[idx];
        float4 s = ((const float4*)bn_sum)[cp];
        float4 q = ((const float4*)bn_sq)[cp];
        float4 g = ((const float4*)gamma)[cp];
        float4 b = ((const float4*)beta)[cp];
        float4 o;
        { float mu = s.x * invN; float var = q.x * invN - mu * mu;
          o.x = (v.x - mu) * rsqrtf(var + BN_EPS) * g.x + b.x; }
        { float mu = s.y * invN; float var = q.y * invN - mu * mu;
          o.y = (v.y - mu) * rsqrtf(var + BN_EPS) * g.y + b.y; }
        { float mu = s.z * invN; float var = q.z * invN - mu * mu;
          o.z = (v.z - mu) * rsqrtf(var + BN_EPS) * g.z + b.z; }
        { float mu = s.w * invN; float var = q.w * invN - mu * mu;
          o.w = (v.w - mu) * rsqrtf(var + BN_EPS) * g.w + b.w; }
        ((float4*)out)[idx] = o;
    }
}

extern "C" void kernel_launch(void* const* d_in, const int* in_sizes, int n_in,
                              void* d_out, int out_size, void* d_ws, size_t ws_size,
                              hipStream_t stream) {
    const float* x     = (const float*)d_in[0];
    const int*   ei    = (const int*)d_in[1];
    const float* Wl    = (const float*)d_in[2];
    const float* bl    = (const float*)d_in[3];
    const float* Wr    = (const float*)d_in[4];
    const float* gamma = (const float*)d_in[5];
    const float* beta  = (const float*)d_in[6];

    float* out_raw = (float*)d_out;                       // [NN][DD] x_raw
    float* out_bn  = out_raw + (size_t)NN * DD;           // [NN][DD] x_deskewed
    unsigned* xq   = (unsigned*)d_out;                    // fp8[NN*128] in out_raw half
    int*      cntM = (int*)((char*)d_out + 16000000);     // int[NBLK*NB]
    int*      gbR  = (int*)((char*)d_out + 20000000);     // int[NBLK*NB]
    unsigned* bin  = (unsigned*)out_bn;                   // uint[NE]
    unsigned* aggb = (unsigned*)out_bn;                   // bf16[NN*128] packed
    unsigned* xb   = (unsigned*)((char*)out_bn + (size_t)NN * DD * 2); // bf16[NN*128]

    char* ws = (char*)d_ws;
    int*   cnt    = (int*)(ws + WS_CNT);
    int*   coff   = (int*)(ws + WS_COFF);
    int*   flag   = (int*)(ws + WS_FLAG);
    float* bn_sum = (float*)(ws + WS_BNSUM);
    float* bn_sq  = (float*)(ws + WS_BNSQ);
    int*   deg    = (int*)(ws + WS_DEG);
    int*   off    = (int*)(ws + WS_OFF);
    int*   csr    = (int*)(ws + WS_CSR);
    unsigned short* Wt = (unsigned short*)(ws + WS_WT);

    hipMemsetAsync(d_ws, 0, WS_ZERO, stream);

    k_detect<<<1, 64, 0, stream>>>(ei, flag);
    k_prep<<<2048 + 128, 256, 0, stream>>>(x, xb, xq, Wl, Wr, Wt);
    k_binA<<<NBLK, 256, 0, stream>>>(ei, flag, cntM);
    k_colscan<<<NB, 512, 0, stream>>>(cntM, gbR, cnt);
    k_scan<<<1, 256, 0, stream>>>(cnt, coff);
    k_binB<<<NBLK, 256, 0, stream>>>(ei, flag, cntM, gbR, coff, bin);
    k_csr<<<NB, 256, 0, stream>>>(bin, coff, csr, deg, off);
    k_agg<<<(NN * 64 + 255) / 256, 256, 0, stream>>>((const uint2*)xq, csr, deg, off, aggb);
    k_gemm<<<(NN + 127) / 128, 256, 0, stream>>>((const unsigned short*)aggb,
                                                 (const unsigned short*)xb,
                                                 Wt, bl, out_raw, bn_sum, bn_sq);
    k_norm<<<4096, 256, 0, stream>>>(out_raw, bn_sum, bn_sq, gamma, beta, out_bn);
}